// Round 1
// baseline (3324.162 us; speedup 1.0000x reference)
//
#include <hip/hip_runtime.h>
#include <cmath>

#define DEV __device__ __forceinline__

// ---------------- constants ----------------
// B=8, H=32, W=32, DIM=512, L=1024, DI=1024, DS=16, DCONV=4, DTR=32, HID=1024
#define Bc    8
#define Lc    1024
#define DIMc  512
#define DIc   1024
#define DSc   16
#define DTRc  32
#define HIDc  1024
#define BLc   (Bc*Lc)   // 8192

DEV float gelu_f(float x){ return 0.5f*x*(1.f+erff(x*0.70710678118654752f)); }
DEV float silu_f(float x){ return x / (1.f + __expf(-x)); }
DEV float softplus_f(float x){ return (x > 20.f) ? x : log1pf(__expf(x)); }

// ---------------- block reduce (256 threads, 4 waves) ----------------
DEV void block_sum2(float& a, float& b) {
  #pragma unroll
  for (int off = 32; off > 0; off >>= 1) {
    a += __shfl_down(a, off, 64);
    b += __shfl_down(b, off, 64);
  }
  __shared__ float sa[4], sb[4];
  int lane = threadIdx.x & 63, w = threadIdx.x >> 6;
  __syncthreads();
  if (lane == 0) { sa[w] = a; sb[w] = b; }
  __syncthreads();
  a = sa[0]+sa[1]+sa[2]+sa[3];
  b = sb[0]+sb[1]+sb[2]+sb[3];
}

// ---------------- generic fp32 GEMM: C = act(A(M,K) * W(N,K)^T + bias) + res ----
// A row-major lda, W row-major ldw (K contiguous), C row-major ldc.
// act: 0 none, 1 gelu, 2 softplus. bias/res may be nullptr.
template<int BM,int BN,int BK,int TM,int TN>
__global__ __launch_bounds__(256) void gemm_k(
    const float* __restrict__ A, int lda,
    const float* __restrict__ W, int ldw,
    float* __restrict__ C, int ldc,
    int K,
    const float* __restrict__ bias,
    const float* __restrict__ res, int ldr,
    int act)
{
  __shared__ float As[BK][BM+4];
  __shared__ float Ws[BK][BN+4];
  const int tid = threadIdx.x;
  const int m0 = blockIdx.y*BM, n0 = blockIdx.x*BN;
  constexpr int TX = BN/TN;
  const int tx = tid % TX, ty = tid / TX;
  float acc[TM][TN];
  #pragma unroll
  for (int i=0;i<TM;i++)
    #pragma unroll
    for (int j=0;j<TN;j++) acc[i][j]=0.f;

  constexpr int KQ = BK/4;
  for (int k0 = 0; k0 < K; k0 += BK) {
    for (int i = tid; i < BM*KQ; i += 256) {
      int row = i / KQ, kq = i % KQ;
      float4 v = *(const float4*)(A + (size_t)(m0+row)*lda + k0 + kq*4);
      As[kq*4+0][row]=v.x; As[kq*4+1][row]=v.y; As[kq*4+2][row]=v.z; As[kq*4+3][row]=v.w;
    }
    for (int i = tid; i < BN*KQ; i += 256) {
      int row = i / KQ, kq = i % KQ;
      float4 v = *(const float4*)(W + (size_t)(n0+row)*ldw + k0 + kq*4);
      Ws[kq*4+0][row]=v.x; Ws[kq*4+1][row]=v.y; Ws[kq*4+2][row]=v.z; Ws[kq*4+3][row]=v.w;
    }
    __syncthreads();
    #pragma unroll
    for (int kk=0; kk<BK; ++kk) {
      float a[TM], bb[TN];
      #pragma unroll
      for (int i=0;i<TM;i++) a[i] = As[kk][ty*TM+i];
      #pragma unroll
      for (int j=0;j<TN;j++) bb[j] = Ws[kk][tx*TN+j];
      #pragma unroll
      for (int i=0;i<TM;i++)
        #pragma unroll
        for (int j=0;j<TN;j++)
          acc[i][j] = fmaf(a[i], bb[j], acc[i][j]);
    }
    __syncthreads();
  }
  #pragma unroll
  for (int i=0;i<TM;i++) {
    const int m = m0 + ty*TM + i;
    #pragma unroll
    for (int j=0;j<TN;j++) {
      const int n = n0 + tx*TN + j;
      float v = acc[i][j];
      if (bias) v += bias[n];
      if (act == 1) v = gelu_f(v);
      else if (act == 2) v = softplus_f(v);
      if (res) v += res[(size_t)m*ldr + n];
      C[(size_t)m*ldc + n] = v;
    }
  }
}

// ---------------- pos hidden: hid[l,d] = gelu(pos6[l] . w1[d] + b1[d]) ---------
__global__ __launch_bounds__(256) void pos_hidden_k(
    const float* __restrict__ w1, const float* __restrict__ b1,
    float* __restrict__ hid)
{
  const float PI = 3.14159265358979323846f;
  int l = blockIdx.x;
  float yi = ((float)(l>>5)+0.5f)/32.f*2.f-1.f;
  float xi = ((float)(l&31)+0.5f)/32.f*2.f-1.f;
  float p[6] = {yi, xi, sinf(PI*yi), cosf(PI*yi), sinf(PI*xi), cosf(PI*xi)};
  for (int d = threadIdx.x; d < DIMc; d += 256) {
    float a = b1[d];
    #pragma unroll
    for (int j=0;j<6;j++) a = fmaf(p[j], w1[d*6+j], a);
    hid[(size_t)l*DIMc + d] = gelu_f(a);
  }
}

// ---------------- LN(tokens)+pos -> scanin ----------------
__global__ __launch_bounds__(256) void ln_in_k(
    const float* __restrict__ x, const float* __restrict__ g,
    const float* __restrict__ bta, const float* __restrict__ pos,
    float* __restrict__ out)
{
  int r = blockIdx.x;
  int t = threadIdx.x;
  const float* xr = x + (size_t)r*DIMc;
  float2 v = *(const float2*)(xr + t*2);
  float s = v.x+v.y, q = v.x*v.x+v.y*v.y;
  block_sum2(s, q);
  float mean = s * (1.f/DIMc);
  float var  = q * (1.f/DIMc) - mean*mean;
  float rstd = rsqrtf(var + 1e-5f);
  int l = r & (Lc-1);
  float2 gg = *(const float2*)(g + t*2);
  float2 bb = *(const float2*)(bta + t*2);
  float2 pp = *(const float2*)(pos + (size_t)l*DIMc + t*2);
  float2 o;
  o.x = (v.x-mean)*rstd*gg.x + bb.x + pp.x;
  o.y = (v.y-mean)*rstd*gg.y + bb.y + pp.y;
  *(float2*)(out + (size_t)r*DIMc + t*2) = o;
}

// ---------------- causal/anticausal depthwise conv + silu ----------------
// xc[b,l,c] = silu(cb[c] + sum_k cw[c,k]*xin[b, l+-..., c]) ; xin = xz[:, :DI]
__global__ __launch_bounds__(256) void conv_k(
    const float* __restrict__ xz, float* __restrict__ xc,
    const float* __restrict__ cw, const float* __restrict__ cb, int dir)
{
  size_t i = (size_t)blockIdx.x*256 + threadIdx.x;  // over B*L*DI
  int c = (int)(i & (DIc-1));
  size_t bl = i >> 10;
  int l = (int)(bl & (Lc-1));
  size_t brow = bl & ~(size_t)(Lc-1);
  float acc = cb[c];
  #pragma unroll
  for (int k=0;k<4;k++){
    int lp = dir ? (l + 3 - k) : (l - 3 + k);
    if (lp >= 0 && lp < Lc)
      acc = fmaf(cw[c*4+k], xz[(brow + lp)*(2*DIc) + c], acc);
  }
  xc[i] = silu_f(acc);
}

// ---------------- selective scan + gating ----------------
// dbuf holds delta on input, gated y on output (in-place per element).
__global__ __launch_bounds__(256) void scan_k(
    const float* __restrict__ proj,   // (B*L,64): [0:32)dt [32:48)Bm [48:64)Cm
    float* __restrict__ dbuf,         // (B*L,DI)
    const float* __restrict__ xc,     // (B*L,DI)
    const float* __restrict__ xz,     // (B*L,2*DI) - z half
    const float* __restrict__ A_log,  // (DI,16)
    const float* __restrict__ Dp,     // (DI)
    int dir)
{
  const int b = blockIdx.y;
  const int c = blockIdx.x*256 + threadIdx.x;
  float A[DSc];
  #pragma unroll
  for (int s=0;s<DSc;s++) A[s] = -__expf(A_log[c*DSc + s]);
  const float Dc = Dp[c];
  float h[DSc];
  #pragma unroll
  for (int s=0;s<DSc;s++) h[s] = 0.f;

  const int CH = 64;
  __shared__ float bc[CH][32];
  for (int l0=0; l0<Lc; l0+=CH) {
    __syncthreads();
    for (int i = threadIdx.x; i < CH*32; i += 256) {
      int st = i >> 5, s = i & 31;
      int l = l0 + st;
      int lr = dir ? (Lc-1-l) : l;
      bc[st][s] = proj[((size_t)b*Lc + lr)*64 + 32 + s];
    }
    __syncthreads();
    for (int st=0; st<CH; ++st) {
      int l = l0 + st;
      int lr = dir ? (Lc-1-l) : l;
      size_t row = (size_t)b*Lc + lr;
      size_t idx = row*DIc + c;
      float d  = dbuf[idx];
      float x  = xc[idx];
      float z  = xz[row*(2*DIc) + DIc + c];
      float dx = d * x;
      float y = 0.f;
      #pragma unroll
      for (int s=0;s<DSc;s++){
        float e = __expf(d*A[s]);
        h[s] = fmaf(h[s], e, dx*bc[st][s]);
        y = fmaf(h[s], bc[st][16+s], y);
      }
      float yg = (y + x*Dc) * silu_f(z);
      dbuf[idx] = yg;
    }
  }
}

// ---------------- broadcast pos into concat[:,1024:1536] ----------------
__global__ __launch_bounds__(256) void pos_bcast_k(
    const float* __restrict__ pos, float* __restrict__ concat)
{
  size_t i = (size_t)blockIdx.x*256 + threadIdx.x;  // over B*L*DIM
  size_t r = i >> 9;
  int d = (int)(i & (DIMc-1));
  concat[r*(3*DIMc) + 2*DIMc + d] = pos[(r & (Lc-1))*DIMc + d];
}

// ---------------- fused dn-LN then fn-LN ----------------
__global__ __launch_bounds__(256) void ln_dnfn_k(
    const float* __restrict__ mixout,
    const float* __restrict__ dng, const float* __restrict__ dnb,
    const float* __restrict__ fng, const float* __restrict__ fnb,
    float* __restrict__ delta, float* __restrict__ tb)
{
  int r = blockIdx.x;
  int t = threadIdx.x;
  float2 v = *(const float2*)(mixout + (size_t)r*DIMc + t*2);
  float s = v.x+v.y, q = v.x*v.x+v.y*v.y;
  block_sum2(s, q);
  float mean = s * (1.f/DIMc);
  float var  = q * (1.f/DIMc) - mean*mean;
  float rstd = rsqrtf(var + 1e-5f);
  float2 gg = *(const float2*)(dng + t*2);
  float2 bb = *(const float2*)(dnb + t*2);
  float d0 = (v.x-mean)*rstd*gg.x + bb.x;
  float d1 = (v.y-mean)*rstd*gg.y + bb.y;
  *(float2*)(delta + (size_t)r*DIMc + t*2) = make_float2(d0, d1);
  // second LN over delta
  float s2 = d0+d1, q2 = d0*d0+d1*d1;
  block_sum2(s2, q2);
  float mean2 = s2 * (1.f/DIMc);
  float var2  = q2 * (1.f/DIMc) - mean2*mean2;
  float rstd2 = rsqrtf(var2 + 1e-5f);
  float2 g2 = *(const float2*)(fng + t*2);
  float2 b2 = *(const float2*)(fnb + t*2);
  float2 o;
  o.x = (d0-mean2)*rstd2*g2.x + b2.x;
  o.y = (d1-mean2)*rstd2*g2.y + b2.y;
  *(float2*)(tb + (size_t)r*DIMc + t*2) = o;
}

// ---------------- launch helpers ----------------
static inline void gemm128(const float* A,int lda,const float* W,int ldw,
                           float* C,int ldc,int M,int N,int K,
                           const float* bias,const float* res,int ldr,int act,
                           hipStream_t s){
  dim3 g(N/128, M/128);
  gemm_k<128,128,8,8,8><<<g,256,0,s>>>(A,lda,W,ldw,C,ldc,K,bias,res,ldr,act);
}
static inline void gemm64(const float* A,int lda,const float* W,int ldw,
                          float* C,int ldc,int M,int N,int K,
                          const float* bias,const float* res,int ldr,int act,
                          hipStream_t s){
  dim3 g(N/64, M/64);
  gemm_k<64,64,16,4,4><<<g,256,0,s>>>(A,lda,W,ldw,C,ldc,K,bias,res,ldr,act);
}

extern "C" void kernel_launch(void* const* d_in, const int* in_sizes, int n_in,
                              void* d_out, int out_size, void* d_ws, size_t ws_size,
                              hipStream_t stream) {
  (void)in_sizes; (void)n_in; (void)out_size; (void)ws_size;
  const float* tokens   = (const float*)d_in[0];
  const float* in_g     = (const float*)d_in[3];
  const float* in_b     = (const float*)d_in[4];
  const float* pos_w1   = (const float*)d_in[5];
  const float* pos_b1   = (const float*)d_in[6];
  const float* pos_w2   = (const float*)d_in[7];
  const float* pos_b2   = (const float*)d_in[8];
  const float* m_in_w   = (const float*)d_in[9];
  const float* m_conv_w = (const float*)d_in[10];
  const float* m_conv_b = (const float*)d_in[11];
  const float* m_xproj_w= (const float*)d_in[12];
  const float* m_dt_w   = (const float*)d_in[13];
  const float* m_dt_b   = (const float*)d_in[14];
  const float* m_A_log  = (const float*)d_in[15];
  const float* m_D      = (const float*)d_in[16];
  const float* m_out_w  = (const float*)d_in[17];
  const float* mix_w    = (const float*)d_in[18];
  const float* mix_b    = (const float*)d_in[19];
  const float* dn_g     = (const float*)d_in[20];
  const float* dn_b     = (const float*)d_in[21];
  const float* fn_g     = (const float*)d_in[22];
  const float* fn_b     = (const float*)d_in[23];
  const float* ffn_w1   = (const float*)d_in[24];
  const float* ffn_b1   = (const float*)d_in[25];
  const float* ffn_w2   = (const float*)d_in[26];
  const float* ffn_b2   = (const float*)d_in[27];
  float* out = (float*)d_out;

  float* ws = (float*)d_ws;
  float* pos    = ws;                                  // 1024*512
  float* scanin = pos    + (size_t)Lc*DIMc;            // 8192*512
  float* concat = scanin + (size_t)BLc*DIMc;           // 8192*1536
  float* xz     = concat + (size_t)BLc*3*DIMc;         // 8192*2048
  float* xc     = xz     + (size_t)BLc*2*DIc;          // 8192*1024
  float* proj   = xc     + (size_t)BLc*DIc;            // 8192*64
  float* dbuf   = proj   + (size_t)BLc*64;             // 8192*1024
  // reused regions (xz free before/after mamba passes):
  float* poshid = xz;                                  // 1024*512
  float* mixout = xz;                                  // 8192*512
  float* tbuf   = xz + (size_t)BLc*DIMc;               // 8192*512
  float* ffnhid = xz + (size_t)BLc*2*DIMc;             // 8192*1024
  float* delta  = dbuf;                                // 8192*512

  // 1) positional embedding
  pos_hidden_k<<<Lc, 256, 0, stream>>>(pos_w1, pos_b1, poshid);
  gemm128(poshid, DIMc, pos_w2, DIMc, pos, DIMc, Lc, DIMc, DIMc,
          pos_b2, nullptr, 0, 0, stream);

  // 2) scan_in = LN(tokens) + pos
  ln_in_k<<<BLc, 256, 0, stream>>>(tokens, in_g, in_b, pos, scanin);

  // 3) two mamba directions
  for (int dir = 0; dir < 2; ++dir) {
    const float* in_w  = m_in_w   + (size_t)dir*2*DIc*DIMc;
    const float* cw    = m_conv_w + (size_t)dir*DIc*4;
    const float* cb    = m_conv_b + (size_t)dir*DIc;
    const float* xpw   = m_xproj_w+ (size_t)dir*64*DIc;
    const float* dtw   = m_dt_w   + (size_t)dir*DIc*DTRc;
    const float* dtb   = m_dt_b   + (size_t)dir*DIc;
    const float* Alog  = m_A_log  + (size_t)dir*DIc*DSc;
    const float* Dp    = m_D      + (size_t)dir*DIc;
    const float* outw  = m_out_w  + (size_t)dir*DIMc*DIc;

    // xz = scanin @ in_w^T   (8192 x 2048)
    gemm128(scanin, DIMc, in_w, DIMc, xz, 2*DIc, BLc, 2*DIc, DIMc,
            nullptr, nullptr, 0, 0, stream);
    // xc = silu(conv(xz[:, :DI]))
    conv_k<<<(BLc*DIc)/256, 256, 0, stream>>>(xz, xc, cw, cb, dir);
    // proj = xc @ xproj^T    (8192 x 64)
    gemm64(xc, DIc, xpw, DIc, proj, 64, BLc, 64, DIc,
           nullptr, nullptr, 0, 0, stream);
    // dbuf = softplus(proj[:, :32] @ dt_w^T + dt_b)   (8192 x 1024)
    gemm128(proj, 64, dtw, DTRc, dbuf, DIc, BLc, DIc, DTRc,
            dtb, nullptr, 0, 2, stream);
    // selective scan + gating (in-place into dbuf)
    scan_k<<<dim3(DIc/256, Bc), 256, 0, stream>>>(proj, dbuf, xc, xz, Alog, Dp, dir);
    // concat[:, dir*512 : dir*512+512] = dbuf @ out_w^T
    gemm128(dbuf, DIc, outw, DIc, concat + (size_t)dir*DIMc, 3*DIMc,
            BLc, DIMc, DIc, nullptr, nullptr, 0, 0, stream);
  }

  // 4) concat[:, 1024:1536] = pos (broadcast over batch)
  pos_bcast_k<<<(BLc*DIMc)/256, 256, 0, stream>>>(pos, concat);

  // 5) mixout = concat @ mix_w^T + mix_b   (8192 x 512)
  gemm128(concat, 3*DIMc, mix_w, 3*DIMc, mixout, DIMc, BLc, DIMc, 3*DIMc,
          mix_b, nullptr, 0, 0, stream);

  // 6) delta = LN_dn(mixout); tbuf = LN_fn(delta)
  ln_dnfn_k<<<BLc, 256, 0, stream>>>(mixout, dn_g, dn_b, fn_g, fn_b, delta, tbuf);

  // 7) ffnhid = gelu(tbuf @ ffn_w1^T + b1)   (8192 x 1024)
  gemm128(tbuf, DIMc, ffn_w1, DIMc, ffnhid, HIDc, BLc, HIDc, DIMc,
          ffn_b1, nullptr, 0, 1, stream);

  // 8) out = delta + ffnhid @ ffn_w2^T + b2  (8192 x 512)
  gemm128(ffnhid, HIDc, ffn_w2, HIDc, out, DIMc, BLc, DIMc, HIDc,
          ffn_b2, delta, DIMc, 0, stream);
}

// Round 2
// 1290.264 us; speedup vs baseline: 2.5763x; 2.5763x over previous
//
#include <hip/hip_runtime.h>
#include <hip/hip_bf16.h>
#include <cmath>

#define DEV __device__ __forceinline__

// B=8, H=32, W=32, DIM=512, L=1024, DI=1024, DS=16, DCONV=4, DTR=32, HID=1024
#define Bc    8
#define Lc    1024
#define DIMc  512
#define DIc   1024
#define DSc   16
#define DTRc  32
#define HIDc  1024
#define BLc   (Bc*Lc)   // 8192

typedef __attribute__((ext_vector_type(8))) short bf16x8;
typedef __attribute__((ext_vector_type(4))) float f32x4;

DEV float gelu_f(float x){ return 0.5f*x*(1.f+erff(x*0.70710678118654752f)); }
DEV float silu_f(float x){ return x / (1.f + __expf(-x)); }
DEV float softplus_f(float x){ return (x > 20.f) ? x : log1pf(__expf(x)); }

#define GLOAD16(gp, lp) __builtin_amdgcn_global_load_lds( \
    (__attribute__((address_space(1))) const void*)(gp), \
    (__attribute__((address_space(3))) void*)(lp), 16, 0, 0)

// ---------------- block reduce (256 threads, 4 waves) ----------------
DEV void block_sum2(float& a, float& b) {
  #pragma unroll
  for (int off = 32; off > 0; off >>= 1) {
    a += __shfl_down(a, off, 64);
    b += __shfl_down(b, off, 64);
  }
  __shared__ float sa[4], sb[4];
  int lane = threadIdx.x & 63, w = threadIdx.x >> 6;
  __syncthreads();
  if (lane == 0) { sa[w] = a; sb[w] = b; }
  __syncthreads();
  a = sa[0]+sa[1]+sa[2]+sa[3];
  b = sb[0]+sb[1]+sb[2]+sb[3];
}

// =================== bf16 MFMA GEMM ===================
// C(M,N) = act(A(M,K)bf16 * W(N,K)bf16^T + bias) + res ; writes fp32 and/or bf16.
// BM = WGM*TM*16, BN = WGN*TN*16. 256 threads = 4 waves in WGM x WGN grid.
// K-major inputs, K % 32 == 0, staging via global_load_lds width=16 (m97 recipe).
template<int WGM,int WGN,int TM,int TN>
__global__ __launch_bounds__(256) void mgemm_k(
    const __hip_bfloat16* __restrict__ A, int lda,
    const __hip_bfloat16* __restrict__ W, int ldw,
    float* __restrict__ Cf, __hip_bfloat16* __restrict__ Cb, int ldc,
    int K,
    const float* __restrict__ bias,
    const float* __restrict__ res, int ldr,
    int act)
{
  constexpr int BM = WGM*TM*16;
  constexpr int BN = WGN*TN*16;
  __shared__ __align__(16) unsigned short As[BM*32];
  __shared__ __align__(16) unsigned short Ws[BN*32];
  const int tid  = threadIdx.x;
  const int lane = tid & 63, wave = tid >> 6;
  const int wm = wave / WGN, wn = wave % WGN;
  const int m0 = blockIdx.y*BM, n0 = blockIdx.x*BN;

  f32x4 acc[TM][TN] = {};

  const int srow = lane >> 2;        // 0..15  (row within 16-row chunk)
  const int scol = (lane & 3) * 8;   // 0,8,16,24 (k offset, 8 bf16 = 16B)
  const int fr = lane & 15, fk = (lane >> 4) * 8;

  for (int k0 = 0; k0 < K; k0 += 32) {
    __syncthreads();
    #pragma unroll
    for (int r0 = wave*16; r0 < BM; r0 += 64)
      GLOAD16(A + (size_t)(m0 + r0 + srow)*lda + k0 + scol, &As[r0*32]);
    #pragma unroll
    for (int r0 = wave*16; r0 < BN; r0 += 64)
      GLOAD16(W + (size_t)(n0 + r0 + srow)*ldw + k0 + scol, &Ws[r0*32]);
    __syncthreads();
    bf16x8 af[TM], bfr[TN];
    #pragma unroll
    for (int i = 0; i < TM; ++i)
      af[i] = *(const bf16x8*)&As[(wm*TM*16 + i*16 + fr)*32 + fk];
    #pragma unroll
    for (int j = 0; j < TN; ++j)
      bfr[j] = *(const bf16x8*)&Ws[(wn*TN*16 + j*16 + fr)*32 + fk];
    #pragma unroll
    for (int i = 0; i < TM; ++i)
      #pragma unroll
      for (int j = 0; j < TN; ++j)
        acc[i][j] = __builtin_amdgcn_mfma_f32_16x16x32_bf16(af[i], bfr[j], acc[i][j], 0, 0, 0);
  }

  const int cr = (lane >> 4) * 4;   // row base (C/D layout: row=(lane>>4)*4+reg)
  const int cc = lane & 15;         // col = lane&15
  #pragma unroll
  for (int j = 0; j < TN; ++j) {
    const int n = n0 + wn*TN*16 + j*16 + cc;
    const float bv = bias ? bias[n] : 0.f;
    #pragma unroll
    for (int i = 0; i < TM; ++i) {
      const int mB = m0 + wm*TM*16 + i*16 + cr;
      #pragma unroll
      for (int r = 0; r < 4; ++r) {
        float v = acc[i][j][r] + bv;
        if (act == 1) v = gelu_f(v);
        if (res) v += res[(size_t)(mB+r)*ldr + n];
        if (Cf) Cf[(size_t)(mB+r)*ldc + n] = v;
        if (Cb) Cb[(size_t)(mB+r)*ldc + n] = __float2bfloat16(v);
      }
    }
  }
}

// =================== fp32 GEMM (small shapes: pos, dtproj) ===================
template<int BM,int BN,int BK,int TM,int TN>
__global__ __launch_bounds__(256) void gemm_k(
    const float* __restrict__ A, int lda,
    const float* __restrict__ W, int ldw,
    float* __restrict__ C, int ldc,
    int K,
    const float* __restrict__ bias,
    const float* __restrict__ res, int ldr,
    int act)
{
  __shared__ float As[BK][BM+4];
  __shared__ float Ws[BK][BN+4];
  const int tid = threadIdx.x;
  const int m0 = blockIdx.y*BM, n0 = blockIdx.x*BN;
  constexpr int TX = BN/TN;
  const int tx = tid % TX, ty = tid / TX;
  float acc[TM][TN];
  #pragma unroll
  for (int i=0;i<TM;i++)
    #pragma unroll
    for (int j=0;j<TN;j++) acc[i][j]=0.f;

  constexpr int KQ = BK/4;
  for (int k0 = 0; k0 < K; k0 += BK) {
    for (int i = tid; i < BM*KQ; i += 256) {
      int row = i / KQ, kq = i % KQ;
      float4 v = *(const float4*)(A + (size_t)(m0+row)*lda + k0 + kq*4);
      As[kq*4+0][row]=v.x; As[kq*4+1][row]=v.y; As[kq*4+2][row]=v.z; As[kq*4+3][row]=v.w;
    }
    for (int i = tid; i < BN*KQ; i += 256) {
      int row = i / KQ, kq = i % KQ;
      float4 v = *(const float4*)(W + (size_t)(n0+row)*ldw + k0 + kq*4);
      Ws[kq*4+0][row]=v.x; Ws[kq*4+1][row]=v.y; Ws[kq*4+2][row]=v.z; Ws[kq*4+3][row]=v.w;
    }
    __syncthreads();
    #pragma unroll
    for (int kk=0; kk<BK; ++kk) {
      float a[TM], bb[TN];
      #pragma unroll
      for (int i=0;i<TM;i++) a[i] = As[kk][ty*TM+i];
      #pragma unroll
      for (int j=0;j<TN;j++) bb[j] = Ws[kk][tx*TN+j];
      #pragma unroll
      for (int i=0;i<TM;i++)
        #pragma unroll
        for (int j=0;j<TN;j++)
          acc[i][j] = fmaf(a[i], bb[j], acc[i][j]);
    }
    __syncthreads();
  }
  #pragma unroll
  for (int i=0;i<TM;i++) {
    const int m = m0 + ty*TM + i;
    #pragma unroll
    for (int j=0;j<TN;j++) {
      const int n = n0 + tx*TN + j;
      float v = acc[i][j];
      if (bias) v += bias[n];
      if (act == 1) v = gelu_f(v);
      else if (act == 2) v = softplus_f(v);
      if (res) v += res[(size_t)m*ldr + n];
      C[(size_t)m*ldc + n] = v;
    }
  }
}

// =================== weight fp32 -> bf16 conversion ===================
#define W_INW_OFF   0
#define W_INW_N     (2*2048*512)
#define W_OUTW_OFF  (W_INW_OFF + W_INW_N)
#define W_OUTW_N    (2*512*1024)
#define W_MIX_OFF   (W_OUTW_OFF + W_OUTW_N)
#define W_MIX_N     (512*1536)
#define W_F1_OFF    (W_MIX_OFF + W_MIX_N)
#define W_F1_N      (1024*512)
#define W_F2_OFF    (W_F1_OFF + W_F1_N)
#define W_F2_N      (512*1024)
#define W_XP_OFF    (W_F2_OFF + W_F2_N)
#define W_XP_N      (2*64*1024)
#define W_TOTAL     (W_XP_OFF + W_XP_N)

__global__ __launch_bounds__(256) void cvt_weights_k(
    const float* __restrict__ inw, const float* __restrict__ outw,
    const float* __restrict__ mixw, const float* __restrict__ f1,
    const float* __restrict__ f2, const float* __restrict__ xp,
    __hip_bfloat16* __restrict__ dst)
{
  int i = blockIdx.x*256 + threadIdx.x;
  if (i >= W_TOTAL) return;
  float v;
  if      (i < W_OUTW_OFF) v = inw[i - W_INW_OFF];
  else if (i < W_MIX_OFF)  v = outw[i - W_OUTW_OFF];
  else if (i < W_F1_OFF)   v = mixw[i - W_MIX_OFF];
  else if (i < W_F2_OFF)   v = f1[i - W_F1_OFF];
  else if (i < W_XP_OFF)   v = f2[i - W_F2_OFF];
  else                     v = xp[i - W_XP_OFF];
  dst[i] = __float2bfloat16(v);
}

// ---------------- pos hidden ----------------
__global__ __launch_bounds__(256) void pos_hidden_k(
    const float* __restrict__ w1, const float* __restrict__ b1,
    float* __restrict__ hid)
{
  const float PI = 3.14159265358979323846f;
  int l = blockIdx.x;
  float yi = ((float)(l>>5)+0.5f)/32.f*2.f-1.f;
  float xi = ((float)(l&31)+0.5f)/32.f*2.f-1.f;
  float p[6] = {yi, xi, sinf(PI*yi), cosf(PI*yi), sinf(PI*xi), cosf(PI*xi)};
  for (int d = threadIdx.x; d < DIMc; d += 256) {
    float a = b1[d];
    #pragma unroll
    for (int j=0;j<6;j++) a = fmaf(p[j], w1[d*6+j], a);
    hid[(size_t)l*DIMc + d] = gelu_f(a);
  }
}

// ---------------- LN(tokens)+pos -> scanin (bf16) ----------------
__global__ __launch_bounds__(256) void ln_in_k(
    const float* __restrict__ x, const float* __restrict__ g,
    const float* __restrict__ bta, const float* __restrict__ pos,
    __hip_bfloat16* __restrict__ outb)
{
  int r = blockIdx.x;
  int t = threadIdx.x;
  const float* xr = x + (size_t)r*DIMc;
  float2 v = *(const float2*)(xr + t*2);
  float s = v.x+v.y, q = v.x*v.x+v.y*v.y;
  block_sum2(s, q);
  float mean = s * (1.f/DIMc);
  float var  = q * (1.f/DIMc) - mean*mean;
  float rstd = rsqrtf(var + 1e-5f);
  int l = r & (Lc-1);
  float2 gg = *(const float2*)(g + t*2);
  float2 bb = *(const float2*)(bta + t*2);
  float2 pp = *(const float2*)(pos + (size_t)l*DIMc + t*2);
  __hip_bfloat162 ob;
  ob.x = __float2bfloat16((v.x-mean)*rstd*gg.x + bb.x + pp.x);
  ob.y = __float2bfloat16((v.y-mean)*rstd*gg.y + bb.y + pp.y);
  *(__hip_bfloat162*)(outb + (size_t)r*DIMc + t*2) = ob;
}

// ---------------- depthwise conv + silu (fp32 + bf16 outputs) ----------------
__global__ __launch_bounds__(256) void conv_k(
    const float* __restrict__ xz, float* __restrict__ xc,
    __hip_bfloat16* __restrict__ xcb,
    const float* __restrict__ cw, const float* __restrict__ cb, int dir)
{
  size_t i = (size_t)blockIdx.x*256 + threadIdx.x;  // over B*L*DI
  int c = (int)(i & (DIc-1));
  size_t bl = i >> 10;
  int l = (int)(bl & (Lc-1));
  size_t brow = bl & ~(size_t)(Lc-1);
  float acc = cb[c];
  #pragma unroll
  for (int k=0;k<4;k++){
    int lp = dir ? (l + 3 - k) : (l - 3 + k);
    if (lp >= 0 && lp < Lc)
      acc = fmaf(cw[c*4+k], xz[(brow + lp)*(2*DIc) + c], acc);
  }
  float v = silu_f(acc);
  xc[i] = v;
  xcb[i] = __float2bfloat16(v);
}

// =================== lane-parallel selective scan ===================
// Block: 256 thr = 16 channels x 16 states of one b. Grid: (DI/16, B).
// Thread (cl, s): h-recurrence for (b, c0+cl, s); y via 16-lane shfl_xor reduce.
__global__ __launch_bounds__(256) void scan2_k(
    const float* __restrict__ proj,   // (B*L,64): [0:32)dt [32:48)Bm [48:64)Cm
    const float* __restrict__ dbuf,   // (B*L,DI) delta (softplus'd)
    const float* __restrict__ xc,     // (B*L,DI)
    const float* __restrict__ xz,     // (B*L,2*DI): z in cols [DI,2DI)
    const float* __restrict__ A_log,  // (DI,16)
    const float* __restrict__ Dp,     // (DI)
    __hip_bfloat16* __restrict__ ybf, // (B*L,DI) gated output (bf16)
    int dir)
{
  const int b  = blockIdx.y;
  const int c0 = blockIdx.x * 16;
  const int t  = threadIdx.x;
  const int s  = t & 15;       // state
  const int cl = t >> 4;       // channel-local 0..15
  const int c  = c0 + cl;

  const float Av = -__expf(A_log[c*DSc + s]);
  const float Dc = Dp[c];
  float h = 0.f;

  const int CH = 64;
  __shared__ float dS[CH][16], xS[CH][16], zS[CH][16], yS[CH][16];
  __shared__ float bcS[CH][32];

  for (int l0 = 0; l0 < Lc; l0 += CH) {
    // ---- stage chunk (float4 coalesced) ----
    for (int i = t; i < CH*4; i += 256) {
      int st = i >> 2, q = i & 3;
      int lr = dir ? (Lc-1-(l0+st)) : (l0+st);
      size_t row = (size_t)b*Lc + lr;
      *(float4*)&dS[st][q*4] = *(const float4*)(dbuf + row*DIc + c0 + q*4);
      *(float4*)&xS[st][q*4] = *(const float4*)(xc   + row*DIc + c0 + q*4);
      *(float4*)&zS[st][q*4] = *(const float4*)(xz   + row*(2*DIc) + DIc + c0 + q*4);
    }
    for (int i = t; i < CH*8; i += 256) {
      int st = i >> 3, q = i & 7;
      int lr = dir ? (Lc-1-(l0+st)) : (l0+st);
      *(float4*)&bcS[st][q*4] = *(const float4*)(proj + ((size_t)b*Lc + lr)*64 + 32 + q*4);
    }
    __syncthreads();
    // ---- sequential recurrence over chunk ----
    for (int st = 0; st < CH; ++st) {
      float d = dS[st][cl];
      float x = xS[st][cl];
      float e = __expf(d * Av);
      h = fmaf(h, e, d * x * bcS[st][s]);
      float y = h * bcS[st][16 + s];
      y += __shfl_xor(y, 1, 64);
      y += __shfl_xor(y, 2, 64);
      y += __shfl_xor(y, 4, 64);
      y += __shfl_xor(y, 8, 64);
      if (s == 0) {
        float z = zS[st][cl];
        yS[st][cl] = (y + x * Dc) * silu_f(z);
      }
    }
    __syncthreads();
    // ---- write out chunk (bf16) ----
    for (int i = t; i < CH*4; i += 256) {
      int st = i >> 2, q = i & 3;
      int lr = dir ? (Lc-1-(l0+st)) : (l0+st);
      size_t row = (size_t)b*Lc + lr;
      __hip_bfloat16 o[4];
      #pragma unroll
      for (int j=0;j<4;j++) o[j] = __float2bfloat16(yS[st][q*4+j]);
      *(ushort4*)(ybf + row*DIc + c0 + q*4) = *(const ushort4*)o;
    }
    __syncthreads();
  }
}

// ---------------- broadcast pos into concat_bf[:,1024:1536] ----------------
__global__ __launch_bounds__(256) void pos_bcast_k(
    const float* __restrict__ pos, __hip_bfloat16* __restrict__ concatb)
{
  size_t i = (size_t)blockIdx.x*256 + threadIdx.x;  // over B*L*DIM
  size_t r = i >> 9;
  int d = (int)(i & (DIMc-1));
  concatb[r*(3*DIMc) + 2*DIMc + d] = __float2bfloat16(pos[(r & (Lc-1))*DIMc + d]);
}

// ---------------- fused dn-LN (fp32 delta) then fn-LN (bf16 tbuf) ----------------
__global__ __launch_bounds__(256) void ln_dnfn_k(
    const float* __restrict__ mixout,
    const float* __restrict__ dng, const float* __restrict__ dnb,
    const float* __restrict__ fng, const float* __restrict__ fnb,
    float* __restrict__ delta, __hip_bfloat16* __restrict__ tb)
{
  int r = blockIdx.x;
  int t = threadIdx.x;
  float2 v = *(const float2*)(mixout + (size_t)r*DIMc + t*2);
  float s = v.x+v.y, q = v.x*v.x+v.y*v.y;
  block_sum2(s, q);
  float mean = s * (1.f/DIMc);
  float var  = q * (1.f/DIMc) - mean*mean;
  float rstd = rsqrtf(var + 1e-5f);
  float2 gg = *(const float2*)(dng + t*2);
  float2 bb = *(const float2*)(dnb + t*2);
  float d0 = (v.x-mean)*rstd*gg.x + bb.x;
  float d1 = (v.y-mean)*rstd*gg.y + bb.y;
  *(float2*)(delta + (size_t)r*DIMc + t*2) = make_float2(d0, d1);
  float s2 = d0+d1, q2 = d0*d0+d1*d1;
  block_sum2(s2, q2);
  float mean2 = s2 * (1.f/DIMc);
  float var2  = q2 * (1.f/DIMc) - mean2*mean2;
  float rstd2 = rsqrtf(var2 + 1e-5f);
  float2 g2 = *(const float2*)(fng + t*2);
  float2 b2 = *(const float2*)(fnb + t*2);
  __hip_bfloat162 ob;
  ob.x = __float2bfloat16((d0-mean2)*rstd2*g2.x + b2.x);
  ob.y = __float2bfloat16((d1-mean2)*rstd2*g2.y + b2.y);
  *(__hip_bfloat162*)(tb + (size_t)r*DIMc + t*2) = ob;
}

// ---------------- launchers ----------------
typedef __hip_bfloat16 bf16;
static inline void mg128(const bf16* A,int lda,const bf16* W,int ldw,
                         float* Cf, bf16* Cb,int ldc,int M,int N,int K,
                         const float* bias,const float* res,int ldr,int act,
                         hipStream_t s){
  dim3 g(N/128, M/128);
  mgemm_k<2,2,4,4><<<g,256,0,s>>>(A,lda,W,ldw,Cf,Cb,ldc,K,bias,res,ldr,act);
}
static inline void mg64n(const bf16* A,int lda,const bf16* W,int ldw,
                         float* Cf, bf16* Cb,int ldc,int M,int N,int K,
                         const float* bias,const float* res,int ldr,int act,
                         hipStream_t s){
  dim3 g(N/64, M/128);
  mgemm_k<4,1,2,4><<<g,256,0,s>>>(A,lda,W,ldw,Cf,Cb,ldc,K,bias,res,ldr,act);
}
static inline void gemm128(const float* A,int lda,const float* W,int ldw,
                           float* C,int ldc,int M,int N,int K,
                           const float* bias,const float* res,int ldr,int act,
                           hipStream_t s){
  dim3 g(N/128, M/128);
  gemm_k<128,128,8,8,8><<<g,256,0,s>>>(A,lda,W,ldw,C,ldc,K,bias,res,ldr,act);
}

extern "C" void kernel_launch(void* const* d_in, const int* in_sizes, int n_in,
                              void* d_out, int out_size, void* d_ws, size_t ws_size,
                              hipStream_t stream) {
  (void)in_sizes; (void)n_in; (void)out_size; (void)ws_size;
  const float* tokens   = (const float*)d_in[0];
  const float* in_g     = (const float*)d_in[3];
  const float* in_b     = (const float*)d_in[4];
  const float* pos_w1   = (const float*)d_in[5];
  const float* pos_b1   = (const float*)d_in[6];
  const float* pos_w2   = (const float*)d_in[7];
  const float* pos_b2   = (const float*)d_in[8];
  const float* m_in_w   = (const float*)d_in[9];
  const float* m_conv_w = (const float*)d_in[10];
  const float* m_conv_b = (const float*)d_in[11];
  const float* m_xproj_w= (const float*)d_in[12];
  const float* m_dt_w   = (const float*)d_in[13];
  const float* m_dt_b   = (const float*)d_in[14];
  const float* m_A_log  = (const float*)d_in[15];
  const float* m_D      = (const float*)d_in[16];
  const float* m_out_w  = (const float*)d_in[17];
  const float* mix_w    = (const float*)d_in[18];
  const float* mix_b    = (const float*)d_in[19];
  const float* dn_g     = (const float*)d_in[20];
  const float* dn_b     = (const float*)d_in[21];
  const float* fn_g     = (const float*)d_in[22];
  const float* fn_b     = (const float*)d_in[23];
  const float* ffn_w1   = (const float*)d_in[24];
  const float* ffn_b1   = (const float*)d_in[25];
  const float* ffn_w2   = (const float*)d_in[26];
  const float* ffn_b2   = (const float*)d_in[27];
  float* out = (float*)d_out;

  // ---- workspace carve (bytes, 256B aligned) ----
  char* p = (char*)d_ws;
  auto carve = [&](size_t bytes)->char* {
    char* r = p; p += (bytes + 255) & ~(size_t)255; return r;
  };
  float* pos      = (float*)carve((size_t)Lc*DIMc*4);        //  2 MB
  bf16*  scaninb  = (bf16* )carve((size_t)BLc*DIMc*2);       //  8 MB
  bf16*  concatb  = (bf16* )carve((size_t)BLc*3*DIMc*2);     // 24 MB
  float* xzf      = (float*)carve((size_t)BLc*2*DIc*4);      // 64 MB (overlaid later)
  float* xcf      = (float*)carve((size_t)BLc*DIc*4);        // 32 MB
  bf16*  xcb      = (bf16* )carve((size_t)BLc*DIc*2);        // 16 MB
  float* projf    = (float*)carve((size_t)BLc*64*4);         //  2 MB
  float* dbuf     = (float*)carve((size_t)BLc*DIc*4);        // 32 MB
  bf16*  ybf      = (bf16* )carve((size_t)BLc*DIc*2);        // 16 MB
  bf16*  wbf      = (bf16* )carve((size_t)W_TOTAL*2);        // ~10 MB
  // overlays in xzf region (free after the two mamba passes / before mix):
  float* poshid   = xzf;                                     //  2 MB (pre-dirs)
  float* mixout   = xzf;                                     // 16 MB
  float* delta    = xzf + (size_t)BLc*DIMc;                  // 16 MB
  bf16*  tbufb    = (bf16*)(xzf + (size_t)2*BLc*DIMc);       //  8 MB
  bf16*  ffnhidb  = (bf16*)(xzf + (size_t)3*BLc*DIMc);       // 16 MB

  const bf16* inw_bf  = wbf + W_INW_OFF;
  const bf16* outw_bf = wbf + W_OUTW_OFF;
  const bf16* mix_bf  = wbf + W_MIX_OFF;
  const bf16* f1_bf   = wbf + W_F1_OFF;
  const bf16* f2_bf   = wbf + W_F2_OFF;
  const bf16* xp_bf   = wbf + W_XP_OFF;

  // 0) weights -> bf16
  cvt_weights_k<<<(W_TOTAL+255)/256, 256, 0, stream>>>(
      m_in_w, m_out_w, mix_w, ffn_w1, ffn_w2, m_xproj_w, wbf);

  // 1) positional embedding (fp32 path, small)
  pos_hidden_k<<<Lc, 256, 0, stream>>>(pos_w1, pos_b1, poshid);
  gemm128(poshid, DIMc, pos_w2, DIMc, pos, DIMc, Lc, DIMc, DIMc,
          pos_b2, nullptr, 0, 0, stream);

  // 2) scan_in = LN(tokens) + pos  -> bf16
  ln_in_k<<<BLc, 256, 0, stream>>>(tokens, in_g, in_b, pos, scaninb);

  // 3) two mamba directions
  for (int dir = 0; dir < 2; ++dir) {
    const bf16*  inw  = inw_bf  + (size_t)dir*2*DIc*DIMc;
    const float* cw   = m_conv_w + (size_t)dir*DIc*4;
    const float* cb   = m_conv_b + (size_t)dir*DIc;
    const bf16*  xpw  = xp_bf   + (size_t)dir*64*DIc;
    const float* dtw  = m_dt_w  + (size_t)dir*DIc*DTRc;
    const float* dtb  = m_dt_b  + (size_t)dir*DIc;
    const float* Alog = m_A_log + (size_t)dir*DIc*DSc;
    const float* Dp   = m_D     + (size_t)dir*DIc;
    const bf16*  outw = outw_bf + (size_t)dir*DIMc*DIc;

    // xz = scanin @ in_w^T  (8192 x 2048, K=512)  [MFMA]
    mg128(scaninb, DIMc, inw, DIMc, xzf, nullptr, 2*DIc, BLc, 2*DIc, DIMc,
          nullptr, nullptr, 0, 0, stream);
    // xc = silu(conv(xz[:, :DI]))  fp32 + bf16
    conv_k<<<(BLc*DIc)/256, 256, 0, stream>>>(xzf, xcf, xcb, cw, cb, dir);
    // proj = xc @ xproj^T  (8192 x 64, K=1024)  [MFMA, BN=64]
    mg64n(xcb, DIc, xpw, DIc, projf, nullptr, 64, BLc, 64, DIc,
          nullptr, nullptr, 0, 0, stream);
    // dbuf = softplus(proj[:, :32] @ dt_w^T + dt_b)  (8192 x 1024, K=32) [fp32]
    gemm128(projf, 64, dtw, DTRc, dbuf, DIc, BLc, DIc, DTRc,
            dtb, nullptr, 0, 2, stream);
    // selective scan + gating -> ybf (bf16)
    scan2_k<<<dim3(DIc/16, Bc), 256, 0, stream>>>(
        projf, dbuf, xcf, xzf, Alog, Dp, ybf, dir);
    // concat[:, dir*512 : +512] = y @ out_w^T  (8192 x 512, K=1024) [MFMA]
    mg128(ybf, DIc, outw, DIc, nullptr, concatb + (size_t)dir*DIMc, 3*DIMc,
          BLc, DIMc, DIc, nullptr, nullptr, 0, 0, stream);
  }

  // 4) concat[:, 1024:1536] = pos broadcast (bf16)
  pos_bcast_k<<<(BLc*DIMc)/256, 256, 0, stream>>>(pos, concatb);

  // 5) mixout = concat @ mix_w^T + mix_b  (8192 x 512, K=1536) [MFMA -> fp32]
  mg128(concatb, 3*DIMc, mix_bf, 3*DIMc, mixout, nullptr, DIMc, BLc, DIMc, 3*DIMc,
        mix_b, nullptr, 0, 0, stream);

  // 6) delta = LN_dn(mixout) fp32 ; tbuf = LN_fn(delta) bf16
  ln_dnfn_k<<<BLc, 256, 0, stream>>>(mixout, dn_g, dn_b, fn_g, fn_b, delta, tbufb);

  // 7) ffnhid = gelu(tbuf @ ffn_w1^T + b1)  (8192 x 1024, K=512) [MFMA -> bf16]
  mg128(tbufb, DIMc, f1_bf, DIMc, nullptr, ffnhidb, HIDc, BLc, HIDc, DIMc,
        ffn_b1, nullptr, 0, 1, stream);

  // 8) out = delta + ffnhid @ ffn_w2^T + b2  (8192 x 512, K=1024) [MFMA -> fp32]
  mg128(ffnhidb, HIDc, f2_bf, HIDc, out, nullptr, DIMc, BLc, DIMc, HIDc,
        ffn_b2, delta, DIMc, 0, stream);
}

// Round 3
// 965.048 us; speedup vs baseline: 3.4446x; 1.3370x over previous
//
#include <hip/hip_runtime.h>
#include <hip/hip_bf16.h>
#include <cmath>

#define DEV __device__ __forceinline__

// B=8, H=32, W=32, DIM=512, L=1024, DI=1024, DS=16, DCONV=4, DTR=32, HID=1024
#define Bc    8
#define Lc    1024
#define DIMc  512
#define DIc   1024
#define DSc   16
#define DTRc  32
#define HIDc  1024
#define BLc   (Bc*Lc)   // 8192
#define Pseg  16
#define SEGL  (Lc/Pseg) // 64
#define CHa   16

typedef __attribute__((ext_vector_type(8))) short bf16x8;
typedef __attribute__((ext_vector_type(4))) float f32x4;
typedef __hip_bfloat16 bf16;

DEV float gelu_f(float x){ return 0.5f*x*(1.f+erff(x*0.70710678118654752f)); }
DEV float silu_f(float x){ return x / (1.f + __expf(-x)); }
DEV float softplus_f(float x){ return (x > 20.f) ? x : log1pf(__expf(x)); }

#define GLOAD16(gp, lp) __builtin_amdgcn_global_load_lds( \
    (__attribute__((address_space(1))) const void*)(gp), \
    (__attribute__((address_space(3))) void*)(lp), 16, 0, 0)

// ---------------- block reduce (256 threads, 4 waves) ----------------
DEV void block_sum2(float& a, float& b) {
  #pragma unroll
  for (int off = 32; off > 0; off >>= 1) {
    a += __shfl_down(a, off, 64);
    b += __shfl_down(b, off, 64);
  }
  __shared__ float sa[4], sb[4];
  int lane = threadIdx.x & 63, w = threadIdx.x >> 6;
  __syncthreads();
  if (lane == 0) { sa[w] = a; sb[w] = b; }
  __syncthreads();
  a = sa[0]+sa[1]+sa[2]+sa[3];
  b = sb[0]+sb[1]+sb[2]+sb[3];
}

// =================== bf16 MFMA GEMM ===================
// C(M,N) = act(A(M,K)bf16 * W(N,K)bf16^T + bias) + res ; fp32 and/or bf16 out.
// act: 0 none, 1 gelu, 2 softplus.
template<int WGM,int WGN,int TM,int TN>
__global__ __launch_bounds__(256) void mgemm_k(
    const bf16* __restrict__ A, int lda,
    const bf16* __restrict__ W, int ldw,
    float* __restrict__ Cf, bf16* __restrict__ Cb, int ldc,
    int K,
    const float* __restrict__ bias,
    const float* __restrict__ res, int ldr,
    int act)
{
  constexpr int BM = WGM*TM*16;
  constexpr int BN = WGN*TN*16;
  __shared__ __align__(16) unsigned short As[BM*32];
  __shared__ __align__(16) unsigned short Ws[BN*32];
  const int tid  = threadIdx.x;
  const int lane = tid & 63, wave = tid >> 6;
  const int wm = wave / WGN, wn = wave % WGN;
  const int m0 = blockIdx.y*BM, n0 = blockIdx.x*BN;

  f32x4 acc[TM][TN] = {};

  const int srow = lane >> 2;
  const int scol = (lane & 3) * 8;
  const int fr = lane & 15, fk = (lane >> 4) * 8;

  for (int k0 = 0; k0 < K; k0 += 32) {
    __syncthreads();
    #pragma unroll
    for (int r0 = wave*16; r0 < BM; r0 += 64)
      GLOAD16(A + (size_t)(m0 + r0 + srow)*lda + k0 + scol, &As[r0*32]);
    #pragma unroll
    for (int r0 = wave*16; r0 < BN; r0 += 64)
      GLOAD16(W + (size_t)(n0 + r0 + srow)*ldw + k0 + scol, &Ws[r0*32]);
    __syncthreads();
    bf16x8 af[TM], bfr[TN];
    #pragma unroll
    for (int i = 0; i < TM; ++i)
      af[i] = *(const bf16x8*)&As[(wm*TM*16 + i*16 + fr)*32 + fk];
    #pragma unroll
    for (int j = 0; j < TN; ++j)
      bfr[j] = *(const bf16x8*)&Ws[(wn*TN*16 + j*16 + fr)*32 + fk];
    #pragma unroll
    for (int i = 0; i < TM; ++i)
      #pragma unroll
      for (int j = 0; j < TN; ++j)
        acc[i][j] = __builtin_amdgcn_mfma_f32_16x16x32_bf16(af[i], bfr[j], acc[i][j], 0, 0, 0);
  }

  const int cr = (lane >> 4) * 4;
  const int cc = lane & 15;
  #pragma unroll
  for (int j = 0; j < TN; ++j) {
    const int n = n0 + wn*TN*16 + j*16 + cc;
    const float bv = bias ? bias[n] : 0.f;
    #pragma unroll
    for (int i = 0; i < TM; ++i) {
      const int mB = m0 + wm*TM*16 + i*16 + cr;
      #pragma unroll
      for (int r = 0; r < 4; ++r) {
        float v = acc[i][j][r] + bv;
        if (act == 1) v = gelu_f(v);
        else if (act == 2) v = softplus_f(v);
        if (res) v += res[(size_t)(mB+r)*ldr + n];
        if (Cf) Cf[(size_t)(mB+r)*ldc + n] = v;
        if (Cb) Cb[(size_t)(mB+r)*ldc + n] = __float2bfloat16(v);
      }
    }
  }
}

// =================== weight fp32 -> bf16 conversion ===================
#define W_INW_OFF   0
#define W_INW_N     (2*2048*512)
#define W_OUTW_OFF  (W_INW_OFF + W_INW_N)
#define W_OUTW_N    (2*512*1024)
#define W_MIX_OFF   (W_OUTW_OFF + W_OUTW_N)
#define W_MIX_N     (512*1536)
#define W_F1_OFF    (W_MIX_OFF + W_MIX_N)
#define W_F1_N      (1024*512)
#define W_F2_OFF    (W_F1_OFF + W_F1_N)
#define W_F2_N      (512*1024)
#define W_XP_OFF    (W_F2_OFF + W_F2_N)
#define W_XP_N      (2*64*1024)
#define W_PW2_OFF   (W_XP_OFF + W_XP_N)
#define W_PW2_N     (512*512)
#define W_TOTAL     (W_PW2_OFF + W_PW2_N)

__global__ __launch_bounds__(256) void cvt_weights_k(
    const float* __restrict__ inw, const float* __restrict__ outw,
    const float* __restrict__ mixw, const float* __restrict__ f1,
    const float* __restrict__ f2, const float* __restrict__ xp,
    const float* __restrict__ pw2,
    bf16* __restrict__ dst)
{
  int i = blockIdx.x*256 + threadIdx.x;
  if (i >= W_TOTAL) return;
  float v;
  if      (i < W_OUTW_OFF) v = inw[i - W_INW_OFF];
  else if (i < W_MIX_OFF)  v = outw[i - W_OUTW_OFF];
  else if (i < W_F1_OFF)   v = mixw[i - W_MIX_OFF];
  else if (i < W_F2_OFF)   v = f1[i - W_F1_OFF];
  else if (i < W_XP_OFF)   v = f2[i - W_F2_OFF];
  else if (i < W_PW2_OFF)  v = xp[i - W_XP_OFF];
  else                     v = pw2[i - W_PW2_OFF];
  dst[i] = __float2bfloat16(v);
}

// ---------- composite dt weight: Wc[d][c][k] = sum_r dt_w[d][c][r]*xpw[d][r][k] ----------
__global__ __launch_bounds__(256) void dtw_comp_k(
    const float* __restrict__ dt_w,   // (2,DI,32)
    const float* __restrict__ xpw,    // (2,64,DI) (rows 0..31 = dt)
    bf16* __restrict__ wc)            // (2,DI,DI)
{
  int g = blockIdx.x*256 + threadIdx.x;
  int k  = g & (DIc-1);
  int cc = (g >> 10) & (DIc-1);
  int d  = g >> 20;
  const float* dtr = dt_w + ((size_t)d*DIc + cc)*32;
  const float* xp  = xpw + (size_t)d*64*DIc;
  float acc = 0.f;
  #pragma unroll 8
  for (int r=0;r<32;r++) acc = fmaf(dtr[r], xp[(size_t)r*DIc + k], acc);
  wc[g] = __float2bfloat16(acc);
}

// ---------------- pos hidden (bf16 out) ----------------
__global__ __launch_bounds__(256) void pos_hidden_k(
    const float* __restrict__ w1, const float* __restrict__ b1,
    bf16* __restrict__ hid)
{
  const float PI = 3.14159265358979323846f;
  int l = blockIdx.x;
  float yi = ((float)(l>>5)+0.5f)/32.f*2.f-1.f;
  float xi = ((float)(l&31)+0.5f)/32.f*2.f-1.f;
  float p[6] = {yi, xi, sinf(PI*yi), cosf(PI*yi), sinf(PI*xi), cosf(PI*xi)};
  for (int d = threadIdx.x; d < DIMc; d += 256) {
    float a = b1[d];
    #pragma unroll
    for (int j=0;j<6;j++) a = fmaf(p[j], w1[d*6+j], a);
    hid[(size_t)l*DIMc + d] = __float2bfloat16(gelu_f(a));
  }
}

// ---------------- LN(tokens)+pos -> scanin (bf16) ----------------
__global__ __launch_bounds__(256) void ln_in_k(
    const float* __restrict__ x, const float* __restrict__ g,
    const float* __restrict__ bta, const float* __restrict__ pos,
    bf16* __restrict__ outb)
{
  int r = blockIdx.x;
  int t = threadIdx.x;
  const float* xr = x + (size_t)r*DIMc;
  float2 v = *(const float2*)(xr + t*2);
  float s = v.x+v.y, q = v.x*v.x+v.y*v.y;
  block_sum2(s, q);
  float mean = s * (1.f/DIMc);
  float var  = q * (1.f/DIMc) - mean*mean;
  float rstd = rsqrtf(var + 1e-5f);
  int l = r & (Lc-1);
  float2 gg = *(const float2*)(g + t*2);
  float2 bb = *(const float2*)(bta + t*2);
  float2 pp = *(const float2*)(pos + (size_t)l*DIMc + t*2);
  __hip_bfloat162 ob;
  ob.x = __float2bfloat16((v.x-mean)*rstd*gg.x + bb.x + pp.x);
  ob.y = __float2bfloat16((v.y-mean)*rstd*gg.y + bb.y + pp.y);
  *(__hip_bfloat162*)(outb + (size_t)r*DIMc + t*2) = ob;
}

// ---------------- depthwise conv + silu (bf16 in, fp32 + bf16 out) ----------------
__global__ __launch_bounds__(256) void conv_k(
    const bf16* __restrict__ xzb, float* __restrict__ xc,
    bf16* __restrict__ xcb,
    const float* __restrict__ cw, const float* __restrict__ cb, int dir)
{
  size_t i = (size_t)blockIdx.x*256 + threadIdx.x;  // over B*L*DI
  int c = (int)(i & (DIc-1));
  size_t bl = i >> 10;
  int l = (int)(bl & (Lc-1));
  size_t brow = bl & ~(size_t)(Lc-1);
  float acc = cb[c];
  #pragma unroll
  for (int k=0;k<4;k++){
    int lp = dir ? (l + 3 - k) : (l - 3 + k);
    if (lp >= 0 && lp < Lc)
      acc = fmaf(cw[c*4+k], __bfloat162float(xzb[(brow + lp)*(2*DIc) + c]), acc);
  }
  float v = silu_f(acc);
  xc[i] = v;
  xcb[i] = __float2bfloat16(v);
}

// =================== Pass A: segmented local scan (channel/thread) ===================
// grid (DI/256, B, Pseg). Writes y_local, inclusive prefix sd (may alias dbuf),
// per-segment h_final and sdTot.
__global__ __launch_bounds__(256) void scanA_k(
    const float* __restrict__ projbc,  // (B*L,32): [0:16)Bm [16:32)Cm
    const float* __restrict__ dbuf,    // (B*L,DI) delta fp32
    float* __restrict__ sdbuf,         // (B*L,DI) (alias of dbuf OK: row-disjoint)
    const float* __restrict__ xcf,     // (B*L,DI)
    const float* __restrict__ A_log,   // (DI,16)
    float* __restrict__ ylocal,        // (B*L,DI)
    float* __restrict__ hfin,          // (P,B,DI,16)
    float* __restrict__ sdtot,         // (P,B,DI)
    int dir)
{
  const int t  = threadIdx.x;
  const int c0 = blockIdx.x*256;
  const int c  = c0 + t;
  const int b  = blockIdx.y;
  const int seg= blockIdx.z;

  float A[16];
  #pragma unroll
  for (int s=0;s<16;s++) A[s] = -__expf(A_log[c*16+s]);
  float h[16];
  #pragma unroll
  for (int s=0;s<16;s++) h[s]=0.f;
  float sd = 0.f;

  __shared__ float dS[CHa][256], xS[CHa][256];
  __shared__ float bcS[CHa][32];

  const int lbase = seg*SEGL;
  for (int l0 = 0; l0 < SEGL; l0 += CHa) {
    for (int i = t; i < CHa*64; i += 256) {
      int st = i >> 6, q = (i & 63)*4;
      int l = lbase + l0 + st;
      int lr = dir ? (Lc-1-l) : l;
      size_t row = (size_t)b*Lc + lr;
      *(float4*)&dS[st][q] = *(const float4*)(dbuf + row*DIc + c0 + q);
      *(float4*)&xS[st][q] = *(const float4*)(xcf  + row*DIc + c0 + q);
    }
    for (int i = t; i < CHa*8; i += 256) {
      int st = i >> 3, q = (i & 7)*4;
      int l = lbase + l0 + st;
      int lr = dir ? (Lc-1-l) : l;
      *(float4*)&bcS[st][q] = *(const float4*)(projbc + ((size_t)b*Lc + lr)*32 + q);
    }
    __syncthreads();
    for (int st = 0; st < CHa; ++st) {
      float d = dS[st][t];
      float x = xS[st][t];
      sd += d;
      float dx = d*x;
      float Bs[16], Cs[16];
      #pragma unroll
      for (int q=0;q<4;q++){
        *(float4*)&Bs[q*4] = *(const float4*)&bcS[st][q*4];
        *(float4*)&Cs[q*4] = *(const float4*)&bcS[st][16+q*4];
      }
      float y = 0.f;
      #pragma unroll
      for (int s=0;s<16;s++){
        float e = __expf(d*A[s]);
        h[s] = fmaf(h[s], e, dx*Bs[s]);
        y = fmaf(h[s], Cs[s], y);
      }
      int l = lbase + l0 + st;
      int lr = dir ? (Lc-1-l) : l;
      size_t row = (size_t)b*Lc + lr;
      ylocal[row*DIc + c] = y;
      sdbuf[row*DIc + c]  = sd;
    }
    __syncthreads();
  }
  size_t hb = (size_t)(seg*Bc + b)*DIc + c;
  #pragma unroll
  for (int q=0;q<4;q++)
    *(float4*)(hfin + hb*16 + q*4) = *(const float4*)&h[q*4];
  sdtot[hb] = sd;
}

// =================== Pass B: inter-segment combine ===================
__global__ __launch_bounds__(256) void scanB_k(
    const float* __restrict__ hfin,   // (P,B,DI,16)
    const float* __restrict__ sdtot,  // (P,B,DI)
    const float* __restrict__ A_log,  // (DI,16)
    float* __restrict__ h0buf)        // (P,B,DI,16)
{
  int g = blockIdx.x*256 + threadIdx.x;   // B*DI*16 = 131072
  int s = g & 15;
  int c = (g >> 4) & (DIc-1);
  int b = g >> 14;
  float A = -__expf(A_log[c*16+s]);
  float h = 0.f;
  for (int seg=0; seg<Pseg; ++seg) {
    size_t base = (size_t)(seg*Bc+b)*DIc + c;
    h0buf[base*16 + s] = h;
    float E = __expf(A * sdtot[base]);
    h = fmaf(h, E, hfin[base*16 + s]);
  }
}

// =================== Pass C: parallel correction + gating ===================
__global__ __launch_bounds__(256) void scanC_k(
    const float* __restrict__ projbc,  // (B*L,32)
    const float* __restrict__ sdbuf,   // (B*L,DI)
    const float* __restrict__ ylocal,  // (B*L,DI)
    const bf16* __restrict__ xcb,      // (B*L,DI)
    const bf16* __restrict__ xzb,      // (B*L,2DI): z in cols [DI,2DI)
    const float* __restrict__ h0buf,   // (P,B,DI,16)
    const float* __restrict__ A_log,
    const float* __restrict__ Dp,
    bf16* __restrict__ ybf,            // (B*L,DI)
    int dir)
{
  const int t = threadIdx.x;
  const int c = blockIdx.x*256 + t;
  const int b = blockIdx.y;
  const int seg = blockIdx.z;
  float A[16], h0[16];
  #pragma unroll
  for (int s=0;s<16;s++) A[s] = -__expf(A_log[c*16+s]);
  size_t hb = (size_t)(seg*Bc+b)*DIc + c;
  #pragma unroll
  for (int q=0;q<4;q++)
    *(float4*)&h0[q*4] = *(const float4*)(h0buf + hb*16 + q*4);
  const float Dc = Dp[c];

  for (int l0=0; l0<SEGL; ++l0) {
    int l = seg*SEGL + l0;
    int lr = dir ? (Lc-1-l) : l;
    size_t row = (size_t)b*Lc + lr;
    float sd = sdbuf[row*DIc + c];
    float yl = ylocal[row*DIc + c];
    float x  = __bfloat162float(xcb[row*DIc + c]);
    float z  = __bfloat162float(xzb[row*(2*DIc) + DIc + c]);
    float Cs[16];
    #pragma unroll
    for (int q=0;q<4;q++)
      *(float4*)&Cs[q*4] = *(const float4*)(projbc + row*32 + 16 + q*4);
    float corr = 0.f;
    #pragma unroll
    for (int s=0;s<16;s++)
      corr = fmaf(h0[s]*Cs[s], __expf(A[s]*sd), corr);
    float y = yl + corr;
    float o = (y + x*Dc) * silu_f(z);
    ybf[row*DIc + c] = __float2bfloat16(o);
  }
}

// ---------------- broadcast pos into concat_bf[:,1024:1536] ----------------
__global__ __launch_bounds__(256) void pos_bcast_k(
    const float* __restrict__ pos, bf16* __restrict__ concatb)
{
  size_t i = (size_t)blockIdx.x*256 + threadIdx.x;
  size_t r = i >> 9;
  int d = (int)(i & (DIMc-1));
  concatb[r*(3*DIMc) + 2*DIMc + d] = __float2bfloat16(pos[(r & (Lc-1))*DIMc + d]);
}

// ---------------- fused dn-LN (fp32 delta) then fn-LN (bf16 tbuf) ----------------
__global__ __launch_bounds__(256) void ln_dnfn_k(
    const float* __restrict__ mixout,
    const float* __restrict__ dng, const float* __restrict__ dnb,
    const float* __restrict__ fng, const float* __restrict__ fnb,
    float* __restrict__ delta, bf16* __restrict__ tb)
{
  int r = blockIdx.x;
  int t = threadIdx.x;
  float2 v = *(const float2*)(mixout + (size_t)r*DIMc + t*2);
  float s = v.x+v.y, q = v.x*v.x+v.y*v.y;
  block_sum2(s, q);
  float mean = s * (1.f/DIMc);
  float var  = q * (1.f/DIMc) - mean*mean;
  float rstd = rsqrtf(var + 1e-5f);
  float2 gg = *(const float2*)(dng + t*2);
  float2 bb = *(const float2*)(dnb + t*2);
  float d0 = (v.x-mean)*rstd*gg.x + bb.x;
  float d1 = (v.y-mean)*rstd*gg.y + bb.y;
  *(float2*)(delta + (size_t)r*DIMc + t*2) = make_float2(d0, d1);
  float s2 = d0+d1, q2 = d0*d0+d1*d1;
  block_sum2(s2, q2);
  float mean2 = s2 * (1.f/DIMc);
  float var2  = q2 * (1.f/DIMc) - mean2*mean2;
  float rstd2 = rsqrtf(var2 + 1e-5f);
  float2 g2 = *(const float2*)(fng + t*2);
  float2 b2 = *(const float2*)(fnb + t*2);
  __hip_bfloat162 ob;
  ob.x = __float2bfloat16((d0-mean2)*rstd2*g2.x + b2.x);
  ob.y = __float2bfloat16((d1-mean2)*rstd2*g2.y + b2.y);
  *(__hip_bfloat162*)(tb + (size_t)r*DIMc + t*2) = ob;
}

// ---------------- launchers ----------------
static inline void mg128(const bf16* A,int lda,const bf16* W,int ldw,
                         float* Cf, bf16* Cb,int ldc,int M,int N,int K,
                         const float* bias,const float* res,int ldr,int act,
                         hipStream_t s){
  dim3 g(N/128, M/128);
  mgemm_k<2,2,4,4><<<g,256,0,s>>>(A,lda,W,ldw,Cf,Cb,ldc,K,bias,res,ldr,act);
}
static inline void mg_n32(const bf16* A,int lda,const bf16* W,int ldw,
                          float* Cf, bf16* Cb,int ldc,int M,int K,
                          hipStream_t s){
  dim3 g(1, M/64);  // BM=64, BN=32
  mgemm_k<4,1,1,2><<<g,256,0,s>>>(A,lda,W,ldw,Cf,Cb,ldc,K,nullptr,nullptr,0,0);
}

extern "C" void kernel_launch(void* const* d_in, const int* in_sizes, int n_in,
                              void* d_out, int out_size, void* d_ws, size_t ws_size,
                              hipStream_t stream) {
  (void)in_sizes; (void)n_in; (void)out_size; (void)ws_size;
  const float* tokens   = (const float*)d_in[0];
  const float* in_g     = (const float*)d_in[3];
  const float* in_b     = (const float*)d_in[4];
  const float* pos_w1   = (const float*)d_in[5];
  const float* pos_b1   = (const float*)d_in[6];
  const float* pos_w2   = (const float*)d_in[7];
  const float* pos_b2   = (const float*)d_in[8];
  const float* m_in_w   = (const float*)d_in[9];
  const float* m_conv_w = (const float*)d_in[10];
  const float* m_conv_b = (const float*)d_in[11];
  const float* m_xproj_w= (const float*)d_in[12];
  const float* m_dt_w   = (const float*)d_in[13];
  const float* m_dt_b   = (const float*)d_in[14];
  const float* m_A_log  = (const float*)d_in[15];
  const float* m_D      = (const float*)d_in[16];
  const float* m_out_w  = (const float*)d_in[17];
  const float* mix_w    = (const float*)d_in[18];
  const float* mix_b    = (const float*)d_in[19];
  const float* dn_g     = (const float*)d_in[20];
  const float* dn_b     = (const float*)d_in[21];
  const float* fn_g     = (const float*)d_in[22];
  const float* fn_b     = (const float*)d_in[23];
  const float* ffn_w1   = (const float*)d_in[24];
  const float* ffn_b1   = (const float*)d_in[25];
  const float* ffn_w2   = (const float*)d_in[26];
  const float* ffn_b2   = (const float*)d_in[27];
  float* out = (float*)d_out;

  char* p = (char*)d_ws;
  auto carve = [&](size_t bytes)->char* {
    char* r = p; p += (bytes + 255) & ~(size_t)255; return r;
  };
  float* pos      = (float*)carve((size_t)Lc*DIMc*4);            //  2 MB
  bf16*  scaninb  = (bf16* )carve((size_t)BLc*DIMc*2);           //  8 MB
  bf16*  concatb  = (bf16* )carve((size_t)BLc*3*DIMc*2);         // 24 MB
  bf16*  xzb      = (bf16* )carve((size_t)BLc*2*DIc*2);          // 32 MB (overlaid later)
  float* xcf      = (float*)carve((size_t)BLc*DIc*4);            // 32 MB (overlaid later)
  bf16*  xcb      = (bf16* )carve((size_t)BLc*DIc*2);            // 16 MB
  float* projf    = (float*)carve((size_t)BLc*32*4);             //  1 MB
  float* dbuf     = (float*)carve((size_t)BLc*DIc*4);            // 32 MB (sd aliases)
  float* ylocal   = (float*)carve((size_t)BLc*DIc*4);            // 32 MB
  float* hfin     = (float*)carve((size_t)Pseg*Bc*DIc*16*4);     //  8 MB
  float* h0buf    = (float*)carve((size_t)Pseg*Bc*DIc*16*4);     //  8 MB
  float* sdtot    = (float*)carve((size_t)Pseg*Bc*DIc*4);        //  0.5 MB
  bf16*  ybf      = (bf16* )carve((size_t)BLc*DIc*2);            // 16 MB
  bf16*  wbf      = (bf16* )carve((size_t)W_TOTAL*2);            // ~11 MB
  bf16*  wcomp    = (bf16* )carve((size_t)2*DIc*DIc*2);          //  4 MB
  // overlays:
  bf16*  poshidb  = xzb;                                         // pre-dirs
  float* mixout   = (float*)xzb;                                 // post-dirs, 16 MB
  float* delta    = (float*)xzb + (size_t)BLc*DIMc;              // 16 MB
  bf16*  tbufb    = (bf16*)xcf;                                  //  8 MB
  bf16*  ffnhidb  = (bf16*)((float*)xcf + (size_t)BLc*DIMc);     // 16 MB

  const bf16* inw_bf  = wbf + W_INW_OFF;
  const bf16* outw_bf = wbf + W_OUTW_OFF;
  const bf16* mix_bf  = wbf + W_MIX_OFF;
  const bf16* f1_bf   = wbf + W_F1_OFF;
  const bf16* f2_bf   = wbf + W_F2_OFF;
  const bf16* xp_bf   = wbf + W_XP_OFF;
  const bf16* pw2_bf  = wbf + W_PW2_OFF;

  // 0) weights -> bf16 ; composite dt weight
  cvt_weights_k<<<(W_TOTAL+255)/256, 256, 0, stream>>>(
      m_in_w, m_out_w, mix_w, ffn_w1, ffn_w2, m_xproj_w, pos_w2, wbf);
  dtw_comp_k<<<(2*DIc*DIc)/256, 256, 0, stream>>>(m_dt_w, m_xproj_w, wcomp);

  // 1) positional embedding
  pos_hidden_k<<<Lc, 256, 0, stream>>>(pos_w1, pos_b1, poshidb);
  mg128(poshidb, DIMc, pw2_bf, DIMc, pos, nullptr, DIMc, Lc, DIMc, DIMc,
        pos_b2, nullptr, 0, 0, stream);

  // 2) scan_in = LN(tokens) + pos -> bf16
  ln_in_k<<<BLc, 256, 0, stream>>>(tokens, in_g, in_b, pos, scaninb);

  // 3) two mamba directions
  for (int dir = 0; dir < 2; ++dir) {
    const bf16*  inw  = inw_bf  + (size_t)dir*2*DIc*DIMc;
    const float* cw   = m_conv_w + (size_t)dir*DIc*4;
    const float* cb   = m_conv_b + (size_t)dir*DIc;
    const bf16*  bcw  = xp_bf   + (size_t)dir*64*DIc + (size_t)32*DIc; // rows 32..63
    const bf16*  wcd  = wcomp   + (size_t)dir*DIc*DIc;
    const float* dtb  = m_dt_b  + (size_t)dir*DIc;
    const float* Alog = m_A_log + (size_t)dir*DIc*DSc;
    const float* Dp   = m_D     + (size_t)dir*DIc;
    const bf16*  outw = outw_bf + (size_t)dir*DIMc*DIc;

    // xz = scanin @ in_w^T  (8192 x 2048, K=512) -> bf16
    mg128(scaninb, DIMc, inw, DIMc, nullptr, xzb, 2*DIc, BLc, 2*DIc, DIMc,
          nullptr, nullptr, 0, 0, stream);
    // xc = silu(conv(xz[:, :DI]))
    conv_k<<<(BLc*DIc)/256, 256, 0, stream>>>(xzb, xcf, xcb, cw, cb, dir);
    // projbc = xc @ xproj[32:64]^T  (8192 x 32, K=1024)
    mg_n32(xcb, DIc, bcw, DIc, projf, nullptr, 32, BLc, DIc, stream);
    // delta = softplus(xc @ (dt_w@xpw_dt)^T + dt_b)  (8192 x 1024, K=1024)
    mg128(xcb, DIc, wcd, DIc, dbuf, nullptr, DIc, BLc, DIc, DIc,
          dtb, nullptr, 0, 2, stream);
    // chunked scan: A (local) -> B (combine) -> C (correct+gate)
    scanA_k<<<dim3(DIc/256, Bc, Pseg), 256, 0, stream>>>(
        projf, dbuf, dbuf /*sd in-place*/, xcf, Alog, ylocal, hfin, sdtot, dir);
    scanB_k<<<(Bc*DIc*16)/256, 256, 0, stream>>>(hfin, sdtot, Alog, h0buf);
    scanC_k<<<dim3(DIc/256, Bc, Pseg), 256, 0, stream>>>(
        projf, dbuf, ylocal, xcb, xzb, h0buf, Alog, Dp, ybf, dir);
    // concat[:, dir*512:+512] = y @ out_w^T  (8192 x 512, K=1024)
    mg128(ybf, DIc, outw, DIc, nullptr, concatb + (size_t)dir*DIMc, 3*DIMc,
          BLc, DIMc, DIc, nullptr, nullptr, 0, 0, stream);
  }

  // 4) concat[:, 1024:1536] = pos broadcast
  pos_bcast_k<<<(BLc*DIMc)/256, 256, 0, stream>>>(pos, concatb);

  // 5) mixout = concat @ mix_w^T + mix_b
  mg128(concatb, 3*DIMc, mix_bf, 3*DIMc, mixout, nullptr, DIMc, BLc, DIMc, 3*DIMc,
        mix_b, nullptr, 0, 0, stream);

  // 6) delta = LN_dn(mixout) ; tbuf = LN_fn(delta)
  ln_dnfn_k<<<BLc, 256, 0, stream>>>(mixout, dn_g, dn_b, fn_g, fn_b, delta, tbufb);

  // 7) ffnhid = gelu(tbuf @ ffn_w1^T + b1)
  mg128(tbufb, DIMc, f1_bf, DIMc, nullptr, ffnhidb, HIDc, BLc, HIDc, DIMc,
        ffn_b1, nullptr, 0, 1, stream);

  // 8) out = delta + ffnhid @ ffn_w2^T + b2
  mg128(ffnhidb, HIDc, f2_bf, HIDc, out, nullptr, DIMc, BLc, DIMc, HIDc,
        ffn_b2, delta, DIMc, 0, stream);
}

// Round 4
// 734.868 us; speedup vs baseline: 4.5235x; 1.3132x over previous
//
#include <hip/hip_runtime.h>
#include <hip/hip_bf16.h>
#include <cmath>

#define DEV __device__ __forceinline__

// B=8, H=32, W=32, DIM=512, L=1024, DI=1024, DS=16, DCONV=4, DTR=32, HID=1024
#define Bc    8
#define Lc    1024
#define DIMc  512
#define DIc   1024
#define DSc   16
#define DTRc  32
#define HIDc  1024
#define BLc   (Bc*Lc)   // 8192
#define Pseg  16
#define SEGL  (Lc/Pseg) // 64
#define CHa   16

typedef __attribute__((ext_vector_type(8))) short bf16x8;
typedef __attribute__((ext_vector_type(4))) float f32x4;
typedef __hip_bfloat16 bf16;

DEV float gelu_f(float x){ return 0.5f*x*(1.f+erff(x*0.70710678118654752f)); }
DEV float silu_f(float x){ return x / (1.f + __expf(-x)); }
DEV float softplus_f(float x){ return (x > 20.f) ? x : __logf(1.f + __expf(x)); }
DEV float bfu2f(unsigned short u){ union{unsigned u32; float f;} x; x.u32=(unsigned)u<<16; return x.f; }
DEV unsigned short f2bu(float f){ bf16 b=__float2bfloat16(f); return *(unsigned short*)&b; }

#define GLOAD16(gp, lp) __builtin_amdgcn_global_load_lds( \
    (__attribute__((address_space(1))) const void*)(gp), \
    (__attribute__((address_space(3))) void*)(lp), 16, 0, 0)

// ---------------- block reduce (256 threads, 4 waves) ----------------
DEV void block_sum2(float& a, float& b) {
  #pragma unroll
  for (int off = 32; off > 0; off >>= 1) {
    a += __shfl_down(a, off, 64);
    b += __shfl_down(b, off, 64);
  }
  __shared__ float sa[4], sb[4];
  int lane = threadIdx.x & 63, w = threadIdx.x >> 6;
  __syncthreads();
  if (lane == 0) { sa[w] = a; sb[w] = b; }
  __syncthreads();
  a = sa[0]+sa[1]+sa[2]+sa[3];
  b = sb[0]+sb[1]+sb[2]+sb[3];
}

// =================== bf16 MFMA GEMM ===================
// C(M,N) = act(A(M,K)bf16 * W(N,K)bf16^T + bias) + res[(m&rmask)] ; fp32/bf16 out.
// act: 0 none, 1 gelu, 2 softplus.
// Operand-swapped MFMA: D row=n-index, col=m-index -> lane holds one C-row,
// 4 consecutive C-cols => vector epilogue stores (no write-allocate RMW).
// XCD swizzle: flat%8 XCD gets a contiguous M-slice for L2 A-locality.
template<int WGM,int WGN,int TM,int TN>
__global__ __launch_bounds__(256) void mgemm_k(
    const bf16* __restrict__ A, int lda,
    const bf16* __restrict__ W, int ldw,
    float* __restrict__ Cf, bf16* __restrict__ Cb, int ldc,
    int K,
    const float* __restrict__ bias,
    const float* __restrict__ res, int ldr, int rmask,
    int act)
{
  constexpr int BM = WGM*TM*16;
  constexpr int BN = WGN*TN*16;
  __shared__ __align__(16) unsigned short As[BM*32];
  __shared__ __align__(16) unsigned short Ws[BN*32];
  int bx, by;
  {
    unsigned nx = gridDim.x, ny = gridDim.y;
    unsigned flat = blockIdx.y*nx + blockIdx.x;
    if ((ny & 7u) == 0u) {
      unsigned q = flat & 7u, idx = flat >> 3, r8 = ny >> 3;
      by = (int)(q*r8 + idx / nx); bx = (int)(idx % nx);
    } else { bx = blockIdx.x; by = blockIdx.y; }
  }
  const int tid  = threadIdx.x;
  const int lane = tid & 63, wave = tid >> 6;
  const int wm = wave / WGN, wn = wave % WGN;
  const int m0 = by*BM, n0 = bx*BN;

  f32x4 acc[TM][TN] = {};

  const int srow = lane >> 2;
  const int scol = (lane & 3) * 8;
  const int fr = lane & 15, fk = (lane >> 4) * 8;

  for (int k0 = 0; k0 < K; k0 += 32) {
    __syncthreads();
    #pragma unroll
    for (int r0 = wave*16; r0 < BM; r0 += 64)
      GLOAD16(A + (size_t)(m0 + r0 + srow)*lda + k0 + scol, &As[r0*32]);
    #pragma unroll
    for (int r0 = wave*16; r0 < BN; r0 += 64)
      GLOAD16(W + (size_t)(n0 + r0 + srow)*ldw + k0 + scol, &Ws[r0*32]);
    __syncthreads();
    bf16x8 af[TM], bfr[TN];
    #pragma unroll
    for (int i = 0; i < TM; ++i)
      af[i] = *(const bf16x8*)&As[(wm*TM*16 + i*16 + fr)*32 + fk];
    #pragma unroll
    for (int j = 0; j < TN; ++j)
      bfr[j] = *(const bf16x8*)&Ws[(wn*TN*16 + j*16 + fr)*32 + fk];
    #pragma unroll
    for (int i = 0; i < TM; ++i)
      #pragma unroll
      for (int j = 0; j < TN; ++j)
        acc[i][j] = __builtin_amdgcn_mfma_f32_16x16x32_bf16(bfr[j], af[i], acc[i][j], 0, 0, 0);
  }

  // epilogue: lane holds C[m][n..n+3], m = tile + (lane&15), n = tile + (lane>>4)*4
  const int em = lane & 15;
  const int en = (lane >> 4) * 4;
  #pragma unroll
  for (int i = 0; i < TM; ++i) {
    const int m = m0 + wm*TM*16 + i*16 + em;
    #pragma unroll
    for (int j = 0; j < TN; ++j) {
      const int n = n0 + wn*TN*16 + j*16 + en;
      float v0 = acc[i][j][0], v1 = acc[i][j][1], v2 = acc[i][j][2], v3 = acc[i][j][3];
      if (bias) {
        float4 bv = *(const float4*)(bias + n);
        v0 += bv.x; v1 += bv.y; v2 += bv.z; v3 += bv.w;
      }
      if (act == 1) { v0=gelu_f(v0); v1=gelu_f(v1); v2=gelu_f(v2); v3=gelu_f(v3); }
      else if (act == 2) { v0=softplus_f(v0); v1=softplus_f(v1); v2=softplus_f(v2); v3=softplus_f(v3); }
      if (res) {
        float4 rv = *(const float4*)(res + (size_t)(m & rmask)*ldr + n);
        v0 += rv.x; v1 += rv.y; v2 += rv.z; v3 += rv.w;
      }
      if (Cf) {
        float4 o = make_float4(v0, v1, v2, v3);
        *(float4*)(Cf + (size_t)m*ldc + n) = o;
      }
      if (Cb) {
        ushort4 o;
        o.x = f2bu(v0); o.y = f2bu(v1); o.z = f2bu(v2); o.w = f2bu(v3);
        *(ushort4*)(Cb + (size_t)m*ldc + n) = o;
      }
    }
  }
}

// =================== weight fp32 -> bf16 conversion ===================
#define W_INW_OFF   0
#define W_INW_N     (2*2048*512)
#define W_OUTW_OFF  (W_INW_OFF + W_INW_N)
#define W_OUTW_N    (2*512*1024)
#define W_MIX_OFF   (W_OUTW_OFF + W_OUTW_N)
#define W_MIX_N     (512*1536)
#define W_F1_OFF    (W_MIX_OFF + W_MIX_N)
#define W_F1_N      (1024*512)
#define W_F2_OFF    (W_F1_OFF + W_F1_N)
#define W_F2_N      (512*1024)
#define W_XP_OFF    (W_F2_OFF + W_F2_N)
#define W_XP_N      (2*64*1024)
#define W_PW2_OFF   (W_XP_OFF + W_XP_N)
#define W_PW2_N     (512*512)
#define W_TOTAL     (W_PW2_OFF + W_PW2_N)

__global__ __launch_bounds__(256) void cvt_weights_k(
    const float* __restrict__ inw, const float* __restrict__ outw,
    const float* __restrict__ mixw, const float* __restrict__ f1,
    const float* __restrict__ f2, const float* __restrict__ xp,
    const float* __restrict__ pw2,
    bf16* __restrict__ dst)
{
  int i = blockIdx.x*256 + threadIdx.x;
  if (i >= W_TOTAL) return;
  float v;
  if      (i < W_OUTW_OFF) v = inw[i - W_INW_OFF];
  else if (i < W_MIX_OFF)  v = outw[i - W_OUTW_OFF];
  else if (i < W_F1_OFF)   v = mixw[i - W_MIX_OFF];
  else if (i < W_F2_OFF)   v = f1[i - W_F1_OFF];
  else if (i < W_XP_OFF)   v = f2[i - W_F2_OFF];
  else if (i < W_PW2_OFF)  v = xp[i - W_XP_OFF];
  else                     v = pw2[i - W_PW2_OFF];
  dst[i] = __float2bfloat16(v);
}

// ---------- composite dt weight: Wc[d][c][k] = sum_r dt_w[d][c][r]*xpw[d][r][k] ----------
__global__ __launch_bounds__(256) void dtw_comp_k(
    const float* __restrict__ dt_w,   // (2,DI,32)
    const float* __restrict__ xpw,    // (2,64,DI) (rows 0..31 = dt)
    bf16* __restrict__ wc)            // (2,DI,DI)
{
  int g = blockIdx.x*256 + threadIdx.x;
  int k  = g & (DIc-1);
  int cc = (g >> 10) & (DIc-1);
  int d  = g >> 20;
  const float* dtr = dt_w + ((size_t)d*DIc + cc)*32;
  const float* xp  = xpw + (size_t)d*64*DIc;
  float acc = 0.f;
  #pragma unroll 8
  for (int r=0;r<32;r++) acc = fmaf(dtr[r], xp[(size_t)r*DIc + k], acc);
  wc[g] = __float2bfloat16(acc);
}

// ---------------- pos hidden (bf16 out) ----------------
__global__ __launch_bounds__(256) void pos_hidden_k(
    const float* __restrict__ w1, const float* __restrict__ b1,
    bf16* __restrict__ hid)
{
  const float PI = 3.14159265358979323846f;
  int l = blockIdx.x;
  float yi = ((float)(l>>5)+0.5f)/32.f*2.f-1.f;
  float xi = ((float)(l&31)+0.5f)/32.f*2.f-1.f;
  float p[6] = {yi, xi, sinf(PI*yi), cosf(PI*yi), sinf(PI*xi), cosf(PI*xi)};
  for (int d = threadIdx.x; d < DIMc; d += 256) {
    float a = b1[d];
    #pragma unroll
    for (int j=0;j<6;j++) a = fmaf(p[j], w1[d*6+j], a);
    hid[(size_t)l*DIMc + d] = __float2bfloat16(gelu_f(a));
  }
}

// ---------------- LN(tokens)+pos -> scanin (bf16) ----------------
__global__ __launch_bounds__(256) void ln_in_k(
    const float* __restrict__ x, const float* __restrict__ g,
    const float* __restrict__ bta, const float* __restrict__ pos,
    bf16* __restrict__ outb)
{
  int r = blockIdx.x;
  int t = threadIdx.x;
  const float* xr = x + (size_t)r*DIMc;
  float2 v = *(const float2*)(xr + t*2);
  float s = v.x+v.y, q = v.x*v.x+v.y*v.y;
  block_sum2(s, q);
  float mean = s * (1.f/DIMc);
  float var  = q * (1.f/DIMc) - mean*mean;
  float rstd = rsqrtf(var + 1e-5f);
  int l = r & (Lc-1);
  float2 gg = *(const float2*)(g + t*2);
  float2 bb = *(const float2*)(bta + t*2);
  float2 pp = *(const float2*)(pos + (size_t)l*DIMc + t*2);
  __hip_bfloat162 ob;
  ob.x = __float2bfloat16((v.x-mean)*rstd*gg.x + bb.x + pp.x);
  ob.y = __float2bfloat16((v.y-mean)*rstd*gg.y + bb.y + pp.y);
  *(__hip_bfloat162*)(outb + (size_t)r*DIMc + t*2) = ob;
}

// ---------------- depthwise conv + silu (merged xz layout) ----------------
// xzb: (B*L, 4096); x part cols [dir*2048, dir*2048+1024)
__global__ __launch_bounds__(256) void conv_k(
    const bf16* __restrict__ xzb, bf16* __restrict__ xcb,
    const float* __restrict__ cw, const float* __restrict__ cb, int dir)
{
  size_t i = (size_t)blockIdx.x*256 + threadIdx.x;  // over B*L*DI
  int c = (int)(i & (DIc-1));
  size_t bl = i >> 10;
  int l = (int)(bl & (Lc-1));
  size_t brow = bl & ~(size_t)(Lc-1);
  const int coloff = dir*2048 + c;
  float acc = cb[c];
  #pragma unroll
  for (int k=0;k<4;k++){
    int lp = dir ? (l + 3 - k) : (l - 3 + k);
    if (lp >= 0 && lp < Lc)
      acc = fmaf(cw[c*4+k], bfu2f(*(const unsigned short*)(xzb + (brow + lp)*4096 + coloff)), acc);
  }
  xcb[i] = __float2bfloat16(silu_f(acc));
}

// =================== Pass A: segmented local scan (channel/thread) ===================
__global__ __launch_bounds__(256) void scanA_k(
    const float* __restrict__ projbc,  // (B*L,32): [0:16)Bm [16:32)Cm
    const bf16* __restrict__ dbuf,     // (B*L,DI) delta bf16
    const bf16* __restrict__ xcb,      // (B*L,DI) bf16
    const float* __restrict__ A_log,   // (DI,16)
    bf16* __restrict__ ylocal,         // (B*L,DI) bf16
    float* __restrict__ hfin,          // (P,B,DI,16)
    float* __restrict__ sdtot,         // (P,B,DI)
    int dir)
{
  const int t  = threadIdx.x;
  const int c0 = blockIdx.x*256;
  const int c  = c0 + t;
  const int b  = blockIdx.y;
  const int seg= blockIdx.z;

  float A[16];
  #pragma unroll
  for (int s=0;s<16;s++) A[s] = -__expf(A_log[c*16+s]);
  float h[16];
  #pragma unroll
  for (int s=0;s<16;s++) h[s]=0.f;
  float sd = 0.f;

  __shared__ unsigned short dS[CHa][256], xS[CHa][256];
  __shared__ float bcS[CHa][32];

  const int lbase = seg*SEGL;
  for (int l0 = 0; l0 < SEGL; l0 += CHa) {
    for (int i = t; i < CHa*32; i += 256) {
      int st = i >> 5, q = (i & 31)*8;
      int l = lbase + l0 + st;
      int lr = dir ? (Lc-1-l) : l;
      size_t row = (size_t)b*Lc + lr;
      *(float4*)&dS[st][q] = *(const float4*)(dbuf + row*DIc + c0 + q);
      *(float4*)&xS[st][q] = *(const float4*)(xcb  + row*DIc + c0 + q);
    }
    for (int i = t; i < CHa*8; i += 256) {
      int st = i >> 3, q = (i & 7)*4;
      int l = lbase + l0 + st;
      int lr = dir ? (Lc-1-l) : l;
      *(float4*)&bcS[st][q] = *(const float4*)(projbc + ((size_t)b*Lc + lr)*32 + q);
    }
    __syncthreads();
    for (int st = 0; st < CHa; ++st) {
      float d = bfu2f(dS[st][t]);
      float x = bfu2f(xS[st][t]);
      sd += d;
      float dx = d*x;
      float Bs[16], Cs[16];
      #pragma unroll
      for (int q=0;q<4;q++){
        *(float4*)&Bs[q*4] = *(const float4*)&bcS[st][q*4];
        *(float4*)&Cs[q*4] = *(const float4*)&bcS[st][16+q*4];
      }
      float y = 0.f;
      #pragma unroll
      for (int s=0;s<16;s++){
        float e = __expf(d*A[s]);
        h[s] = fmaf(h[s], e, dx*Bs[s]);
        y = fmaf(h[s], Cs[s], y);
      }
      int l = lbase + l0 + st;
      int lr = dir ? (Lc-1-l) : l;
      ylocal[((size_t)b*Lc + lr)*DIc + c] = __float2bfloat16(y);
    }
    __syncthreads();
  }
  size_t hb = (size_t)(seg*Bc + b)*DIc + c;
  #pragma unroll
  for (int q=0;q<4;q++)
    *(float4*)(hfin + hb*16 + q*4) = *(const float4*)&h[q*4];
  sdtot[hb] = sd;
}

// =================== Pass B: inter-segment combine ===================
__global__ __launch_bounds__(256) void scanB_k(
    const float* __restrict__ hfin,   // (P,B,DI,16)
    const float* __restrict__ sdtot,  // (P,B,DI)
    const float* __restrict__ A_log,  // (DI,16)
    float* __restrict__ h0buf)        // (P,B,DI,16)
{
  int g = blockIdx.x*256 + threadIdx.x;   // B*DI*16 = 131072
  int s = g & 15;
  int c = (g >> 4) & (DIc-1);
  int b = g >> 14;
  float A = -__expf(A_log[c*16+s]);
  float h = 0.f;
  for (int seg=0; seg<Pseg; ++seg) {
    size_t base = (size_t)(seg*Bc+b)*DIc + c;
    h0buf[base*16 + s] = h;
    float E = __expf(A * sdtot[base]);
    h = fmaf(h, E, hfin[base*16 + s]);
  }
}

// =================== Pass C: parallel correction + gating ===================
__global__ __launch_bounds__(256) void scanC_k(
    const float* __restrict__ projbc,  // (B*L,32)
    const bf16* __restrict__ dbuf,     // (B*L,DI) delta bf16
    const bf16* __restrict__ ylocal,   // (B*L,DI) bf16
    const bf16* __restrict__ xcb,      // (B*L,DI)
    const bf16* __restrict__ xzb,      // (B*L,4096): z at cols dir*2048+1024..
    const float* __restrict__ h0buf,   // (P,B,DI,16)
    const float* __restrict__ A_log,
    const float* __restrict__ Dp,
    bf16* __restrict__ ybf,            // (B*L,DI)
    int dir)
{
  const int t = threadIdx.x;
  const int c = blockIdx.x*256 + t;
  const int b = blockIdx.y;
  const int seg = blockIdx.z;
  float A[16], h0[16];
  #pragma unroll
  for (int s=0;s<16;s++) A[s] = -__expf(A_log[c*16+s]);
  size_t hb = (size_t)(seg*Bc+b)*DIc + c;
  #pragma unroll
  for (int q=0;q<4;q++)
    *(float4*)&h0[q*4] = *(const float4*)(h0buf + hb*16 + q*4);
  const float Dc = Dp[c];
  const int zoff = dir*2048 + 1024 + c;

  float sd = 0.f;
  for (int l0=0; l0<SEGL; ++l0) {
    int l = seg*SEGL + l0;
    int lr = dir ? (Lc-1-l) : l;
    size_t row = (size_t)b*Lc + lr;
    float d  = bfu2f(*(const unsigned short*)(dbuf + row*DIc + c));
    sd += d;
    float yl = bfu2f(*(const unsigned short*)(ylocal + row*DIc + c));
    float x  = bfu2f(*(const unsigned short*)(xcb + row*DIc + c));
    float z  = bfu2f(*(const unsigned short*)(xzb + row*4096 + zoff));
    float Cs[16];
    #pragma unroll
    for (int q=0;q<4;q++)
      *(float4*)&Cs[q*4] = *(const float4*)(projbc + row*32 + 16 + q*4);
    float corr = 0.f;
    #pragma unroll
    for (int s=0;s<16;s++)
      corr = fmaf(h0[s]*Cs[s], __expf(A[s]*sd), corr);
    float y = yl + corr;
    float o = (y + x*Dc) * silu_f(z);
    ybf[row*DIc + c] = __float2bfloat16(o);
  }
}

// ---------------- fused dn-LN (fp32 delta) then fn-LN (bf16 tbuf) ----------------
__global__ __launch_bounds__(256) void ln_dnfn_k(
    const float* __restrict__ mixout,
    const float* __restrict__ dng, const float* __restrict__ dnb,
    const float* __restrict__ fng, const float* __restrict__ fnb,
    float* __restrict__ delta, bf16* __restrict__ tb)
{
  int r = blockIdx.x;
  int t = threadIdx.x;
  float2 v = *(const float2*)(mixout + (size_t)r*DIMc + t*2);
  float s = v.x+v.y, q = v.x*v.x+v.y*v.y;
  block_sum2(s, q);
  float mean = s * (1.f/DIMc);
  float var  = q * (1.f/DIMc) - mean*mean;
  float rstd = rsqrtf(var + 1e-5f);
  float2 gg = *(const float2*)(dng + t*2);
  float2 bb = *(const float2*)(dnb + t*2);
  float d0 = (v.x-mean)*rstd*gg.x + bb.x;
  float d1 = (v.y-mean)*rstd*gg.y + bb.y;
  *(float2*)(delta + (size_t)r*DIMc + t*2) = make_float2(d0, d1);
  float s2 = d0+d1, q2 = d0*d0+d1*d1;
  block_sum2(s2, q2);
  float mean2 = s2 * (1.f/DIMc);
  float var2  = q2 * (1.f/DIMc) - mean2*mean2;
  float rstd2 = rsqrtf(var2 + 1e-5f);
  float2 g2 = *(const float2*)(fng + t*2);
  float2 b2 = *(const float2*)(fnb + t*2);
  __hip_bfloat162 ob;
  ob.x = __float2bfloat16((d0-mean2)*rstd2*g2.x + b2.x);
  ob.y = __float2bfloat16((d1-mean2)*rstd2*g2.y + b2.y);
  *(__hip_bfloat162*)(tb + (size_t)r*DIMc + t*2) = ob;
}

// ---------------- launchers ----------------
#define RM_ALL 0x7fffffff
static inline void mg128(const bf16* A,int lda,const bf16* W,int ldw,
                         float* Cf, bf16* Cb,int ldc,int M,int N,int K,
                         const float* bias,const float* res,int ldr,int rmask,int act,
                         hipStream_t s){
  dim3 g(N/128, M/128);
  mgemm_k<2,2,4,4><<<g,256,0,s>>>(A,lda,W,ldw,Cf,Cb,ldc,K,bias,res,ldr,rmask,act);
}
static inline void mg_n32(const bf16* A,int lda,const bf16* W,int ldw,
                          float* Cf,int ldc,int M,int K, hipStream_t s){
  dim3 g(1, M/64);  // BM=64, BN=32
  mgemm_k<4,1,1,2><<<g,256,0,s>>>(A,lda,W,ldw,Cf,nullptr,ldc,K,nullptr,nullptr,0,RM_ALL,0);
}

extern "C" void kernel_launch(void* const* d_in, const int* in_sizes, int n_in,
                              void* d_out, int out_size, void* d_ws, size_t ws_size,
                              hipStream_t stream) {
  (void)in_sizes; (void)n_in; (void)out_size; (void)ws_size;
  const float* tokens   = (const float*)d_in[0];
  const float* in_g     = (const float*)d_in[3];
  const float* in_b     = (const float*)d_in[4];
  const float* pos_w1   = (const float*)d_in[5];
  const float* pos_b1   = (const float*)d_in[6];
  const float* pos_w2   = (const float*)d_in[7];
  const float* pos_b2   = (const float*)d_in[8];
  const float* m_in_w   = (const float*)d_in[9];
  const float* m_conv_w = (const float*)d_in[10];
  const float* m_conv_b = (const float*)d_in[11];
  const float* m_xproj_w= (const float*)d_in[12];
  const float* m_dt_w   = (const float*)d_in[13];
  const float* m_dt_b   = (const float*)d_in[14];
  const float* m_A_log  = (const float*)d_in[15];
  const float* m_D      = (const float*)d_in[16];
  const float* m_out_w  = (const float*)d_in[17];
  const float* mix_w    = (const float*)d_in[18];
  const float* mix_b    = (const float*)d_in[19];
  const float* dn_g     = (const float*)d_in[20];
  const float* dn_b     = (const float*)d_in[21];
  const float* fn_g     = (const float*)d_in[22];
  const float* fn_b     = (const float*)d_in[23];
  const float* ffn_w1   = (const float*)d_in[24];
  const float* ffn_b1   = (const float*)d_in[25];
  const float* ffn_w2   = (const float*)d_in[26];
  const float* ffn_b2   = (const float*)d_in[27];
  float* out = (float*)d_out;

  char* p = (char*)d_ws;
  auto carve = [&](size_t bytes)->char* {
    char* r = p; p += (bytes + 255) & ~(size_t)255; return r;
  };
  float* pos      = (float*)carve((size_t)Lc*DIMc*4);            //  2 MB
  bf16*  posb     = (bf16* )carve((size_t)Lc*DIMc*2);            //  1 MB
  float* posmix   = (float*)carve((size_t)Lc*DIMc*4);            //  2 MB
  bf16*  poshidb  = (bf16* )carve((size_t)Lc*DIMc*2);            //  1 MB
  bf16*  scaninb  = (bf16* )carve((size_t)BLc*DIMc*2);           //  8 MB
  bf16*  concatb  = (bf16* )carve((size_t)BLc*2*DIMc*2);         // 16 MB
  bf16*  xzb      = (bf16* )carve((size_t)BLc*2*2*DIc*2);        // 64 MB (both dirs; tail overlays)
  bf16*  xcb      = (bf16* )carve((size_t)BLc*DIc*2);            // 16 MB
  float* projf    = (float*)carve((size_t)BLc*32*4);             //  1 MB
  bf16*  dbuf     = (bf16* )carve((size_t)BLc*DIc*2);            // 16 MB
  bf16*  ylocal   = (bf16* )carve((size_t)BLc*DIc*2);            // 16 MB
  float* hfin     = (float*)carve((size_t)Pseg*Bc*DIc*16*4);     //  8 MB
  float* h0buf    = (float*)carve((size_t)Pseg*Bc*DIc*16*4);     //  8 MB
  float* sdtot    = (float*)carve((size_t)Pseg*Bc*DIc*4);        //  0.5 MB
  bf16*  ybf      = (bf16* )carve((size_t)BLc*DIc*2);            // 16 MB
  bf16*  wbf      = (bf16* )carve((size_t)W_TOTAL*2);            // ~11 MB
  bf16*  wcomp    = (bf16* )carve((size_t)2*DIc*DIc*2);          //  4 MB
  // tail overlays in xzb region (free after dir-1 scanC):
  float* mixout   = (float*)xzb;                                 // 16 MB
  float* delta    = (float*)xzb + (size_t)BLc*DIMc;              // 16 MB
  bf16*  tbufb    = (bf16*)((float*)xzb + (size_t)2*BLc*DIMc);   //  8 MB
  bf16*  ffnhidb  = (bf16*)((float*)xzb + (size_t)3*BLc*DIMc);   // 16 MB

  const bf16* inw_bf  = wbf + W_INW_OFF;   // (4096, 512) both dirs contiguous
  const bf16* outw_bf = wbf + W_OUTW_OFF;
  const bf16* mix_bf  = wbf + W_MIX_OFF;   // (512, 1536)
  const bf16* f1_bf   = wbf + W_F1_OFF;
  const bf16* f2_bf   = wbf + W_F2_OFF;
  const bf16* xp_bf   = wbf + W_XP_OFF;
  const bf16* pw2_bf  = wbf + W_PW2_OFF;

  // 0) weights -> bf16 ; composite dt weight
  cvt_weights_k<<<(W_TOTAL+255)/256, 256, 0, stream>>>(
      m_in_w, m_out_w, mix_w, ffn_w1, ffn_w2, m_xproj_w, pos_w2, wbf);
  dtw_comp_k<<<(2*DIc*DIc)/256, 256, 0, stream>>>(m_dt_w, m_xproj_w, wcomp);

  // 1) positional embedding (fp32 + bf16 out)
  pos_hidden_k<<<Lc, 256, 0, stream>>>(pos_w1, pos_b1, poshidb);
  mg128(poshidb, DIMc, pw2_bf, DIMc, pos, posb, DIMc, Lc, DIMc, DIMc,
        pos_b2, nullptr, 0, RM_ALL, 0, stream);
  // posmix = pos @ mix_w[:,1024:1536]^T  (1024 x 512, K=512)
  mg128(posb, DIMc, mix_bf + 1024, 3*DIMc, posmix, nullptr, DIMc, Lc, DIMc, DIMc,
        nullptr, nullptr, 0, RM_ALL, 0, stream);

  // 2) scan_in = LN(tokens) + pos -> bf16
  ln_in_k<<<BLc, 256, 0, stream>>>(tokens, in_g, in_b, pos, scaninb);

  // 3) merged in-proj for BOTH dirs: xz = scanin @ in_w^T  (8192 x 4096, K=512)
  mg128(scaninb, DIMc, inw_bf, DIMc, nullptr, xzb, 2*2*DIc, BLc, 2*2*DIc, DIMc,
        nullptr, nullptr, 0, RM_ALL, 0, stream);

  // 4) two mamba directions
  for (int dir = 0; dir < 2; ++dir) {
    const float* cw   = m_conv_w + (size_t)dir*DIc*4;
    const float* cb   = m_conv_b + (size_t)dir*DIc;
    const bf16*  bcw  = xp_bf   + (size_t)dir*64*DIc + (size_t)32*DIc; // rows 32..63
    const bf16*  wcd  = wcomp   + (size_t)dir*DIc*DIc;
    const float* dtb  = m_dt_b  + (size_t)dir*DIc;
    const float* Alog = m_A_log + (size_t)dir*DIc*DSc;
    const float* Dp   = m_D     + (size_t)dir*DIc;
    const bf16*  outw = outw_bf + (size_t)dir*DIMc*DIc;

    // xc = silu(conv(xz x-part))
    conv_k<<<(BLc*DIc)/256, 256, 0, stream>>>(xzb, xcb, cw, cb, dir);
    // projbc = xc @ xproj[32:64]^T  (8192 x 32, K=1024)
    mg_n32(xcb, DIc, bcw, DIc, projf, 32, BLc, DIc, stream);
    // delta = softplus(xc @ (dt_w@xpw_dt)^T + dt_b)  -> bf16 (8192 x 1024, K=1024)
    mg128(xcb, DIc, wcd, DIc, nullptr, dbuf, DIc, BLc, DIc, DIc,
          dtb, nullptr, 0, RM_ALL, 2, stream);
    // chunked scan: A (local) -> B (combine) -> C (correct+gate)
    scanA_k<<<dim3(DIc/256, Bc, Pseg), 256, 0, stream>>>(
        projf, dbuf, xcb, Alog, ylocal, hfin, sdtot, dir);
    scanB_k<<<(Bc*DIc*16)/256, 256, 0, stream>>>(hfin, sdtot, Alog, h0buf);
    scanC_k<<<dim3(DIc/256, Bc, Pseg), 256, 0, stream>>>(
        projf, dbuf, ylocal, xcb, xzb, h0buf, Alog, Dp, ybf, dir);
    // concat[:, dir*512:+512] = y @ out_w^T  (8192 x 512, K=1024)
    mg128(ybf, DIc, outw, DIc, nullptr, concatb + (size_t)dir*DIMc, 2*DIMc,
          BLc, DIMc, DIc, nullptr, nullptr, 0, RM_ALL, 0, stream);
  }

  // 5) mixout = concat2 @ mix_w[:, :1024]^T + mix_b + posmix[l]  (8192 x 512, K=1024)
  mg128(concatb, 2*DIMc, mix_bf, 3*DIMc, mixout, nullptr, DIMc, BLc, DIMc, 2*DIMc,
        mix_b, posmix, DIMc, Lc-1, 0, stream);

  // 6) delta = LN_dn(mixout) ; tbuf = LN_fn(delta)
  ln_dnfn_k<<<BLc, 256, 0, stream>>>(mixout, dn_g, dn_b, fn_g, fn_b, delta, tbufb);

  // 7) ffnhid = gelu(tbuf @ ffn_w1^T + b1)  (8192 x 1024, K=512)
  mg128(tbufb, DIMc, f1_bf, DIMc, nullptr, ffnhidb, HIDc, BLc, HIDc, DIMc,
        ffn_b1, nullptr, 0, RM_ALL, 1, stream);

  // 8) out = delta + ffnhid @ ffn_w2^T + b2  (8192 x 512, K=1024)
  mg128(ffnhidb, HIDc, f2_bf, HIDc, out, nullptr, DIMc, BLc, DIMc, HIDc,
        ffn_b2, delta, DIMc, RM_ALL, 0, stream);
}

// Round 5
// 660.918 us; speedup vs baseline: 5.0296x; 1.1119x over previous
//
#include <hip/hip_runtime.h>
#include <hip/hip_bf16.h>
#include <cmath>

#define DEV __device__ __forceinline__

// B=8, H=32, W=32, DIM=512, L=1024, DI=1024, DS=16, DCONV=4, DTR=32, HID=1024
#define Bc    8
#define Lc    1024
#define DIMc  512
#define DIc   1024
#define DSc   16
#define DTRc  32
#define HIDc  1024
#define BLc   (Bc*Lc)   // 8192
#define Pseg  16
#define SEGL  (Lc/Pseg) // 64
#define CHa   16

typedef __attribute__((ext_vector_type(8))) short bf16x8;
typedef __attribute__((ext_vector_type(4))) float f32x4;
typedef __hip_bfloat16 bf16;

DEV float gelu_f(float x){ return 0.5f*x*(1.f+erff(x*0.70710678118654752f)); }
DEV float silu_f(float x){ return x / (1.f + __expf(-x)); }
DEV float softplus_f(float x){ return (x > 20.f) ? x : __logf(1.f + __expf(x)); }
DEV float bfu2f(unsigned short u){ union{unsigned u32; float f;} x; x.u32=(unsigned)u<<16; return x.f; }
DEV unsigned short f2bu(float f){ bf16 b=__float2bfloat16(f); return *(unsigned short*)&b; }

#define GLOAD16(gp, lp) __builtin_amdgcn_global_load_lds( \
    (__attribute__((address_space(1))) const void*)(gp), \
    (__attribute__((address_space(3))) void*)(lp), 16, 0, 0)

// ---------------- block reduce (256 threads, 4 waves) ----------------
DEV void block_sum2(float& a, float& b) {
  #pragma unroll
  for (int off = 32; off > 0; off >>= 1) {
    a += __shfl_down(a, off, 64);
    b += __shfl_down(b, off, 64);
  }
  __shared__ float sa[4], sb[4];
  int lane = threadIdx.x & 63, w = threadIdx.x >> 6;
  __syncthreads();
  if (lane == 0) { sa[w] = a; sb[w] = b; }
  __syncthreads();
  a = sa[0]+sa[1]+sa[2]+sa[3];
  b = sb[0]+sb[1]+sb[2]+sb[3];
}

// =================== bf16 MFMA GEMM (strided-batched) ===================
// C(M,N) = act(A(M,K)bf16 * W(N,K)bf16^T + bias) + res[(m&rmask)] ; fp32/bf16 out.
// act: 0 none, 1 gelu, 2 softplus. blockIdx.z = batch (strides in elements).
// Operand-swapped MFMA: lane holds one C-row, 4 consecutive C-cols -> vector
// epilogue. XCD swizzle over (z,y) so each XCD gets a contiguous M-slice.
template<int WGM,int WGN,int TM,int TN>
__global__ __launch_bounds__(256) void mgemm_k(
    const bf16* __restrict__ A, int lda, long sA,
    const bf16* __restrict__ W, int ldw, long sW,
    float* __restrict__ Cf, bf16* __restrict__ Cb, int ldc, long sC,
    int K,
    const float* __restrict__ bias, long sBias,
    const float* __restrict__ res, int ldr, int rmask,
    int act)
{
  constexpr int BM = WGM*TM*16;
  constexpr int BN = WGN*TN*16;
  __shared__ __align__(16) unsigned short As[BM*32];
  __shared__ __align__(16) unsigned short Ws[BN*32];
  int bx, by, bz;
  {
    unsigned nx = gridDim.x, ny = gridDim.y, nz = gridDim.z;
    unsigned nyz = ny*nz;
    unsigned flat = (blockIdx.z*ny + blockIdx.y)*nx + blockIdx.x;
    unsigned byext;
    if ((nyz & 7u) == 0u) {
      unsigned q = flat & 7u, idx = flat >> 3, r8 = nyz >> 3;
      byext = q*r8 + idx / nx; bx = (int)(idx % nx);
    } else { byext = blockIdx.z*ny + blockIdx.y; bx = blockIdx.x; }
    bz = (int)(byext / ny); by = (int)(byext % ny);
  }
  A += (size_t)bz*sA; W += (size_t)bz*sW;
  if (Cf) Cf += (size_t)bz*sC;
  if (Cb) Cb += (size_t)bz*sC;
  if (bias) bias += (size_t)bz*sBias;

  const int tid  = threadIdx.x;
  const int lane = tid & 63, wave = tid >> 6;
  const int wm = wave / WGN, wn = wave % WGN;
  const int m0 = by*BM, n0 = bx*BN;

  f32x4 acc[TM][TN] = {};

  const int srow = lane >> 2;
  const int scol = (lane & 3) * 8;
  const int fr = lane & 15, fk = (lane >> 4) * 8;

  for (int k0 = 0; k0 < K; k0 += 32) {
    __syncthreads();
    #pragma unroll
    for (int r0 = wave*16; r0 < BM; r0 += 64)
      GLOAD16(A + (size_t)(m0 + r0 + srow)*lda + k0 + scol, &As[r0*32]);
    #pragma unroll
    for (int r0 = wave*16; r0 < BN; r0 += 64)
      GLOAD16(W + (size_t)(n0 + r0 + srow)*ldw + k0 + scol, &Ws[r0*32]);
    __syncthreads();
    bf16x8 af[TM], bfr[TN];
    #pragma unroll
    for (int i = 0; i < TM; ++i)
      af[i] = *(const bf16x8*)&As[(wm*TM*16 + i*16 + fr)*32 + fk];
    #pragma unroll
    for (int j = 0; j < TN; ++j)
      bfr[j] = *(const bf16x8*)&Ws[(wn*TN*16 + j*16 + fr)*32 + fk];
    #pragma unroll
    for (int i = 0; i < TM; ++i)
      #pragma unroll
      for (int j = 0; j < TN; ++j)
        acc[i][j] = __builtin_amdgcn_mfma_f32_16x16x32_bf16(bfr[j], af[i], acc[i][j], 0, 0, 0);
  }

  const int em = lane & 15;
  const int en = (lane >> 4) * 4;
  #pragma unroll
  for (int i = 0; i < TM; ++i) {
    const int m = m0 + wm*TM*16 + i*16 + em;
    #pragma unroll
    for (int j = 0; j < TN; ++j) {
      const int n = n0 + wn*TN*16 + j*16 + en;
      float v0 = acc[i][j][0], v1 = acc[i][j][1], v2 = acc[i][j][2], v3 = acc[i][j][3];
      if (bias) {
        float4 bv = *(const float4*)(bias + n);
        v0 += bv.x; v1 += bv.y; v2 += bv.z; v3 += bv.w;
      }
      if (act == 1) { v0=gelu_f(v0); v1=gelu_f(v1); v2=gelu_f(v2); v3=gelu_f(v3); }
      else if (act == 2) { v0=softplus_f(v0); v1=softplus_f(v1); v2=softplus_f(v2); v3=softplus_f(v3); }
      if (res) {
        float4 rv = *(const float4*)(res + (size_t)(m & rmask)*ldr + n);
        v0 += rv.x; v1 += rv.y; v2 += rv.z; v3 += rv.w;
      }
      if (Cf) *(float4*)(Cf + (size_t)m*ldc + n) = make_float4(v0, v1, v2, v3);
      if (Cb) {
        ushort4 o;
        o.x = f2bu(v0); o.y = f2bu(v1); o.z = f2bu(v2); o.w = f2bu(v3);
        *(ushort4*)(Cb + (size_t)m*ldc + n) = o;
      }
    }
  }
}

// =================== weight fp32 -> bf16 conversion ===================
#define W_INW_OFF   0
#define W_INW_N     (2*2048*512)
#define W_OUTW_OFF  (W_INW_OFF + W_INW_N)
#define W_OUTW_N    (2*512*1024)
#define W_MIX_OFF   (W_OUTW_OFF + W_OUTW_N)
#define W_MIX_N     (512*1536)
#define W_F1_OFF    (W_MIX_OFF + W_MIX_N)
#define W_F1_N      (1024*512)
#define W_F2_OFF    (W_F1_OFF + W_F1_N)
#define W_F2_N      (512*1024)
#define W_XP_OFF    (W_F2_OFF + W_F2_N)
#define W_XP_N      (2*64*1024)
#define W_PW2_OFF   (W_XP_OFF + W_XP_N)
#define W_PW2_N     (512*512)
#define W_TOTAL     (W_PW2_OFF + W_PW2_N)

__global__ __launch_bounds__(256) void cvt_weights_k(
    const float* __restrict__ inw, const float* __restrict__ outw,
    const float* __restrict__ mixw, const float* __restrict__ f1,
    const float* __restrict__ f2, const float* __restrict__ xp,
    const float* __restrict__ pw2,
    bf16* __restrict__ dst)
{
  int i = blockIdx.x*256 + threadIdx.x;
  if (i >= W_TOTAL) return;
  float v;
  if      (i < W_OUTW_OFF) v = inw[i - W_INW_OFF];
  else if (i < W_MIX_OFF)  v = outw[i - W_OUTW_OFF];
  else if (i < W_F1_OFF)   v = mixw[i - W_MIX_OFF];
  else if (i < W_F2_OFF)   v = f1[i - W_F1_OFF];
  else if (i < W_XP_OFF)   v = f2[i - W_F2_OFF];
  else if (i < W_PW2_OFF)  v = xp[i - W_XP_OFF];
  else                     v = pw2[i - W_PW2_OFF];
  dst[i] = __float2bfloat16(v);
}

// ---------- composite dt weight: Wc[d][c][k] = sum_r dt_w[d][c][r]*xpw[d][r][k] ----------
__global__ __launch_bounds__(256) void dtw_comp_k(
    const float* __restrict__ dt_w,   // (2,DI,32)
    const float* __restrict__ xpw,    // (2,64,DI) (rows 0..31 = dt)
    bf16* __restrict__ wc)            // (2,DI,DI)
{
  int g = blockIdx.x*256 + threadIdx.x;
  int k  = g & (DIc-1);
  int cc = (g >> 10) & (DIc-1);
  int d  = g >> 20;
  const float* dtr = dt_w + ((size_t)d*DIc + cc)*32;
  const float* xp  = xpw + (size_t)d*64*DIc;
  float acc = 0.f;
  #pragma unroll 8
  for (int r=0;r<32;r++) acc = fmaf(dtr[r], xp[(size_t)r*DIc + k], acc);
  wc[g] = __float2bfloat16(acc);
}

// ---------------- pos hidden (bf16 out) ----------------
__global__ __launch_bounds__(256) void pos_hidden_k(
    const float* __restrict__ w1, const float* __restrict__ b1,
    bf16* __restrict__ hid)
{
  const float PI = 3.14159265358979323846f;
  int l = blockIdx.x;
  float yi = ((float)(l>>5)+0.5f)/32.f*2.f-1.f;
  float xi = ((float)(l&31)+0.5f)/32.f*2.f-1.f;
  float p[6] = {yi, xi, sinf(PI*yi), cosf(PI*yi), sinf(PI*xi), cosf(PI*xi)};
  for (int d = threadIdx.x; d < DIMc; d += 256) {
    float a = b1[d];
    #pragma unroll
    for (int j=0;j<6;j++) a = fmaf(p[j], w1[d*6+j], a);
    hid[(size_t)l*DIMc + d] = __float2bfloat16(gelu_f(a));
  }
}

// ---------------- LN(tokens)+pos -> scanin (bf16) ----------------
__global__ __launch_bounds__(256) void ln_in_k(
    const float* __restrict__ x, const float* __restrict__ g,
    const float* __restrict__ bta, const float* __restrict__ pos,
    bf16* __restrict__ outb)
{
  int r = blockIdx.x;
  int t = threadIdx.x;
  const float* xr = x + (size_t)r*DIMc;
  float2 v = *(const float2*)(xr + t*2);
  float s = v.x+v.y, q = v.x*v.x+v.y*v.y;
  block_sum2(s, q);
  float mean = s * (1.f/DIMc);
  float var  = q * (1.f/DIMc) - mean*mean;
  float rstd = rsqrtf(var + 1e-5f);
  int l = r & (Lc-1);
  float2 gg = *(const float2*)(g + t*2);
  float2 bb = *(const float2*)(bta + t*2);
  float2 pp = *(const float2*)(pos + (size_t)l*DIMc + t*2);
  __hip_bfloat162 ob;
  ob.x = __float2bfloat16((v.x-mean)*rstd*gg.x + bb.x + pp.x);
  ob.y = __float2bfloat16((v.y-mean)*rstd*gg.y + bb.y + pp.y);
  *(__hip_bfloat162*)(outb + (size_t)r*DIMc + t*2) = ob;
}

// ---------------- depthwise conv + silu, both dirs, 8 ch/thread ----------------
// xzb: (B*L, 4096); x part cols [dir*2048, dir*2048+1024). out: xcb2 (2,B*L,DI)
__global__ __launch_bounds__(256) void conv2_k(
    const bf16* __restrict__ xzb, bf16* __restrict__ xcb2,
    const float* __restrict__ cw2, const float* __restrict__ cb2)
{
  const int dir = blockIdx.y;
  int o = blockIdx.x*256 + threadIdx.x;        // octet index over B*L*DI/8
  int c = (o & 127) * 8;
  int bl = o >> 7;
  int l = bl & (Lc-1);
  size_t brow = (size_t)(bl & ~(Lc-1));
  const float* cw = cw2 + (size_t)dir*DIc*4;
  const float* cb = cb2 + (size_t)dir*DIc;

  float acc[8];
  {
    float4 b0 = *(const float4*)(cb + c);
    float4 b1 = *(const float4*)(cb + c + 4);
    acc[0]=b0.x; acc[1]=b0.y; acc[2]=b0.z; acc[3]=b0.w;
    acc[4]=b1.x; acc[5]=b1.y; acc[6]=b1.z; acc[7]=b1.w;
  }
  float wv[8][4];
  #pragma unroll
  for (int j=0;j<8;j++) *(float4*)wv[j] = *(const float4*)(cw + (c+j)*4);

  const size_t coloff = (size_t)dir*2048 + c;
  #pragma unroll
  for (int k=0;k<4;k++){
    int lp = dir ? (l + 3 - k) : (l - 3 + k);
    if (lp >= 0 && lp < Lc) {
      const unsigned short* xp = (const unsigned short*)(xzb + (brow + lp)*4096 + coloff);
      unsigned short xv[8];
      *(float4*)xv = *(const float4*)xp;
      #pragma unroll
      for (int j=0;j<8;j++) acc[j] = fmaf(wv[j][k], bfu2f(xv[j]), acc[j]);
    }
  }
  unsigned short ov[8];
  #pragma unroll
  for (int j=0;j<8;j++) ov[j] = f2bu(silu_f(acc[j]));
  *(float4*)(xcb2 + (size_t)dir*BLc*DIc + (size_t)bl*DIc + c) = *(const float4*)ov;
}

// =================== Pass A: per-segment (h_final, sdTot) only ===================
// grid (DI/256, B, 32): z = dir*16 + seg
__global__ __launch_bounds__(256) void scanA_k(
    const float* __restrict__ projf2,  // (2,B*L,32): [0:16)Bm [16:32)Cm
    const bf16* __restrict__ dbuf2,    // (2,B*L,DI)
    const bf16* __restrict__ xcb2,     // (2,B*L,DI)
    const float* __restrict__ A_log,   // (2,DI,16)
    float* __restrict__ hfin,          // (2,P,B,DI,16)
    float* __restrict__ sdtot)         // (2,P,B,DI)
{
  const int t   = threadIdx.x;
  const int c0  = blockIdx.x*256;
  const int c   = c0 + t;
  const int b   = blockIdx.y;
  const int dir = blockIdx.z >> 4;
  const int seg = blockIdx.z & 15;

  const float* proj = projf2 + (size_t)dir*BLc*32;
  const bf16*  dbuf = dbuf2  + (size_t)dir*BLc*DIc;
  const bf16*  xcb  = xcb2   + (size_t)dir*BLc*DIc;

  float A[16];
  #pragma unroll
  for (int s=0;s<16;s++) A[s] = -__expf(A_log[((size_t)dir*DIc + c)*16 + s]);
  float h[16];
  #pragma unroll
  for (int s=0;s<16;s++) h[s]=0.f;
  float sd = 0.f;

  __shared__ unsigned short dS[CHa][256], xS[CHa][256];
  __shared__ float bS[CHa][16];

  const int lbase = seg*SEGL;
  for (int l0 = 0; l0 < SEGL; l0 += CHa) {
    for (int i = t; i < CHa*32; i += 256) {
      int st = i >> 5, q = (i & 31)*8;
      int l = lbase + l0 + st;
      int lr = dir ? (Lc-1-l) : l;
      size_t row = (size_t)b*Lc + lr;
      *(float4*)&dS[st][q] = *(const float4*)(dbuf + row*DIc + c0 + q);
      *(float4*)&xS[st][q] = *(const float4*)(xcb  + row*DIc + c0 + q);
    }
    for (int i = t; i < CHa*4; i += 256) {
      int st = i >> 2, q = (i & 3)*4;
      int l = lbase + l0 + st;
      int lr = dir ? (Lc-1-l) : l;
      *(float4*)&bS[st][q] = *(const float4*)(proj + ((size_t)b*Lc + lr)*32 + q);
    }
    __syncthreads();
    for (int st = 0; st < CHa; ++st) {
      float d = bfu2f(dS[st][t]);
      float x = bfu2f(xS[st][t]);
      sd += d;
      float dx = d*x;
      float Bs[16];
      #pragma unroll
      for (int q=0;q<4;q++) *(float4*)&Bs[q*4] = *(const float4*)&bS[st][q*4];
      #pragma unroll
      for (int s=0;s<16;s++)
        h[s] = fmaf(h[s], __expf(d*A[s]), dx*Bs[s]);
    }
    __syncthreads();
  }
  size_t hb = (size_t)((dir*Pseg + seg)*Bc + b)*DIc + c;
  #pragma unroll
  for (int q=0;q<4;q++)
    *(float4*)(hfin + hb*16 + q*4) = *(const float4*)&h[q*4];
  sdtot[hb] = sd;
}

// =================== Pass B: inter-segment combine (hfin -> h0, in place) ===========
__global__ __launch_bounds__(256) void scanB_k(
    float* __restrict__ hfin,         // (2,P,B,DI,16) in: h_final, out: h0
    const float* __restrict__ sdtot,  // (2,P,B,DI)
    const float* __restrict__ A_log)  // (2,DI,16)
{
  int g = blockIdx.x*256 + threadIdx.x;   // 2*B*DI*16 = 262144
  int s = g & 15;
  int c = (g >> 4) & (DIc-1);
  int b = (g >> 14) & 7;
  int dir = g >> 17;
  float A = -__expf(A_log[((size_t)dir*DIc + c)*16 + s]);
  float h = 0.f;
  for (int seg=0; seg<Pseg; ++seg) {
    size_t base = (size_t)((dir*Pseg + seg)*Bc + b)*DIc + c;
    float hf = hfin[base*16 + s];
    float E  = __expf(A * sdtot[base]);
    hfin[base*16 + s] = h;          // h0 for this segment
    h = fmaf(h, E, hf);
  }
}

// =================== Pass C: seeded full scan + gating ===================
// grid (DI/256, B, 32): z = dir*16 + seg
__global__ __launch_bounds__(256) void scanC_k(
    const float* __restrict__ projf2,  // (2,B*L,32)
    const bf16* __restrict__ dbuf2,    // (2,B*L,DI)
    const bf16* __restrict__ xcb2,     // (2,B*L,DI)
    const bf16* __restrict__ xzb,      // (B*L,4096): z at cols dir*2048+1024..
    const float* __restrict__ h0buf,   // (2,P,B,DI,16)  (= hfin after scanB)
    const float* __restrict__ A_log,   // (2,DI,16)
    const float* __restrict__ Dp,      // (2,DI)
    bf16* __restrict__ ybf2)           // (2,B*L,DI)
{
  const int t   = threadIdx.x;
  const int c0  = blockIdx.x*256;
  const int c   = c0 + t;
  const int b   = blockIdx.y;
  const int dir = blockIdx.z >> 4;
  const int seg = blockIdx.z & 15;

  const float* proj = projf2 + (size_t)dir*BLc*32;
  const bf16*  dbuf = dbuf2  + (size_t)dir*BLc*DIc;
  const bf16*  xcb  = xcb2   + (size_t)dir*BLc*DIc;
  bf16* ybf = ybf2 + (size_t)dir*BLc*DIc;

  float A[16], h[16];
  #pragma unroll
  for (int s=0;s<16;s++) A[s] = -__expf(A_log[((size_t)dir*DIc + c)*16 + s]);
  size_t hb = (size_t)((dir*Pseg + seg)*Bc + b)*DIc + c;
  #pragma unroll
  for (int q=0;q<4;q++)
    *(float4*)&h[q*4] = *(const float4*)(h0buf + hb*16 + q*4);
  const float Dc = Dp[dir*DIc + c];
  const size_t zcol = (size_t)dir*2048 + 1024 + c0;

  __shared__ unsigned short dS[CHa][256], xS[CHa][256], zS[CHa][256], oS[CHa][256];
  __shared__ float bcS[CHa][32];

  const int lbase = seg*SEGL;
  for (int l0 = 0; l0 < SEGL; l0 += CHa) {
    for (int i = t; i < CHa*32; i += 256) {
      int st = i >> 5, q = (i & 31)*8;
      int l = lbase + l0 + st;
      int lr = dir ? (Lc-1-l) : l;
      size_t row = (size_t)b*Lc + lr;
      *(float4*)&dS[st][q] = *(const float4*)(dbuf + row*DIc + c0 + q);
      *(float4*)&xS[st][q] = *(const float4*)(xcb  + row*DIc + c0 + q);
      *(float4*)&zS[st][q] = *(const float4*)(xzb + row*4096 + zcol + q);
    }
    for (int i = t; i < CHa*8; i += 256) {
      int st = i >> 3, q = (i & 7)*4;
      int l = lbase + l0 + st;
      int lr = dir ? (Lc-1-l) : l;
      *(float4*)&bcS[st][q] = *(const float4*)(proj + ((size_t)b*Lc + lr)*32 + q);
    }
    __syncthreads();
    for (int st = 0; st < CHa; ++st) {
      float d = bfu2f(dS[st][t]);
      float x = bfu2f(xS[st][t]);
      float z = bfu2f(zS[st][t]);
      float dx = d*x;
      float Bs[16], Cs[16];
      #pragma unroll
      for (int q=0;q<4;q++){
        *(float4*)&Bs[q*4] = *(const float4*)&bcS[st][q*4];
        *(float4*)&Cs[q*4] = *(const float4*)&bcS[st][16+q*4];
      }
      float y = 0.f;
      #pragma unroll
      for (int s=0;s<16;s++){
        h[s] = fmaf(h[s], __expf(d*A[s]), dx*Bs[s]);
        y = fmaf(h[s], Cs[s], y);
      }
      oS[st][t] = f2bu((y + x*Dc) * silu_f(z));
    }
    __syncthreads();
    for (int i = t; i < CHa*32; i += 256) {
      int st = i >> 5, q = (i & 31)*8;
      int l = lbase + l0 + st;
      int lr = dir ? (Lc-1-l) : l;
      *(float4*)(ybf + ((size_t)b*Lc + lr)*DIc + c0 + q) = *(const float4*)&oS[st][q];
    }
    __syncthreads();
  }
}

// ---------------- fused dn-LN (fp32 delta) then fn-LN (bf16 tbuf) ----------------
__global__ __launch_bounds__(256) void ln_dnfn_k(
    const float* __restrict__ mixout,
    const float* __restrict__ dng, const float* __restrict__ dnb,
    const float* __restrict__ fng, const float* __restrict__ fnb,
    float* __restrict__ delta, bf16* __restrict__ tb)
{
  int r = blockIdx.x;
  int t = threadIdx.x;
  float2 v = *(const float2*)(mixout + (size_t)r*DIMc + t*2);
  float s = v.x+v.y, q = v.x*v.x+v.y*v.y;
  block_sum2(s, q);
  float mean = s * (1.f/DIMc);
  float var  = q * (1.f/DIMc) - mean*mean;
  float rstd = rsqrtf(var + 1e-5f);
  float2 gg = *(const float2*)(dng + t*2);
  float2 bb = *(const float2*)(dnb + t*2);
  float d0 = (v.x-mean)*rstd*gg.x + bb.x;
  float d1 = (v.y-mean)*rstd*gg.y + bb.y;
  *(float2*)(delta + (size_t)r*DIMc + t*2) = make_float2(d0, d1);
  float s2 = d0+d1, q2 = d0*d0+d1*d1;
  block_sum2(s2, q2);
  float mean2 = s2 * (1.f/DIMc);
  float var2  = q2 * (1.f/DIMc) - mean2*mean2;
  float rstd2 = rsqrtf(var2 + 1e-5f);
  float2 g2 = *(const float2*)(fng + t*2);
  float2 b2 = *(const float2*)(fnb + t*2);
  __hip_bfloat162 ob;
  ob.x = __float2bfloat16((d0-mean2)*rstd2*g2.x + b2.x);
  ob.y = __float2bfloat16((d1-mean2)*rstd2*g2.y + b2.y);
  *(__hip_bfloat162*)(tb + (size_t)r*DIMc + t*2) = ob;
}

// ---------------- launchers ----------------
#define RM_ALL 0x7fffffff
static inline void mg128b(const bf16* A,int lda,long sA,const bf16* W,int ldw,long sW,
                          float* Cf, bf16* Cb,int ldc,long sC,int M,int N,int K,int nb,
                          const float* bias,long sBias,
                          const float* res,int ldr,int rmask,int act,
                          hipStream_t s){
  dim3 g(N/128, M/128, nb);
  mgemm_k<2,2,4,4><<<g,256,0,s>>>(A,lda,sA,W,ldw,sW,Cf,Cb,ldc,sC,K,bias,sBias,res,ldr,rmask,act);
}
static inline void mg128(const bf16* A,int lda,const bf16* W,int ldw,
                         float* Cf, bf16* Cb,int ldc,int M,int N,int K,
                         const float* bias,const float* res,int ldr,int rmask,int act,
                         hipStream_t s){
  mg128b(A,lda,0,W,ldw,0,Cf,Cb,ldc,0,M,N,K,1,bias,0,res,ldr,rmask,act,s);
}
static inline void mg_n32b(const bf16* A,int lda,long sA,const bf16* W,int ldw,long sW,
                           float* Cf,int ldc,long sC,int M,int K,int nb,hipStream_t s){
  dim3 g(1, M/64, nb);  // BM=64, BN=32
  mgemm_k<4,1,1,2><<<g,256,0,s>>>(A,lda,sA,W,ldw,sW,Cf,nullptr,ldc,sC,K,nullptr,0,nullptr,0,RM_ALL,0);
}

extern "C" void kernel_launch(void* const* d_in, const int* in_sizes, int n_in,
                              void* d_out, int out_size, void* d_ws, size_t ws_size,
                              hipStream_t stream) {
  (void)in_sizes; (void)n_in; (void)out_size; (void)ws_size;
  const float* tokens   = (const float*)d_in[0];
  const float* in_g     = (const float*)d_in[3];
  const float* in_b     = (const float*)d_in[4];
  const float* pos_w1   = (const float*)d_in[5];
  const float* pos_b1   = (const float*)d_in[6];
  const float* pos_w2   = (const float*)d_in[7];
  const float* pos_b2   = (const float*)d_in[8];
  const float* m_in_w   = (const float*)d_in[9];
  const float* m_conv_w = (const float*)d_in[10];
  const float* m_conv_b = (const float*)d_in[11];
  const float* m_xproj_w= (const float*)d_in[12];
  const float* m_dt_w   = (const float*)d_in[13];
  const float* m_dt_b   = (const float*)d_in[14];
  const float* m_A_log  = (const float*)d_in[15];
  const float* m_D      = (const float*)d_in[16];
  const float* m_out_w  = (const float*)d_in[17];
  const float* mix_w    = (const float*)d_in[18];
  const float* mix_b    = (const float*)d_in[19];
  const float* dn_g     = (const float*)d_in[20];
  const float* dn_b     = (const float*)d_in[21];
  const float* fn_g     = (const float*)d_in[22];
  const float* fn_b     = (const float*)d_in[23];
  const float* ffn_w1   = (const float*)d_in[24];
  const float* ffn_b1   = (const float*)d_in[25];
  const float* ffn_w2   = (const float*)d_in[26];
  const float* ffn_b2   = (const float*)d_in[27];
  float* out = (float*)d_out;

  char* p = (char*)d_ws;
  auto carve = [&](size_t bytes)->char* {
    char* r = p; p += (bytes + 255) & ~(size_t)255; return r;
  };
  float* pos      = (float*)carve((size_t)Lc*DIMc*4);            //  2 MB
  bf16*  posb     = (bf16* )carve((size_t)Lc*DIMc*2);            //  1 MB
  float* posmix   = (float*)carve((size_t)Lc*DIMc*4);            //  2 MB
  bf16*  poshidb  = (bf16* )carve((size_t)Lc*DIMc*2);            //  1 MB
  bf16*  scaninb  = (bf16* )carve((size_t)BLc*DIMc*2);           //  8 MB
  bf16*  concatb  = (bf16* )carve((size_t)BLc*2*DIMc*2);         // 16 MB
  bf16*  xzb      = (bf16* )carve((size_t)BLc*2*2*DIc*2);        // 64 MB (tail overlays)
  bf16*  xcb2     = (bf16* )carve((size_t)2*BLc*DIc*2);          // 32 MB
  float* projf2   = (float*)carve((size_t)2*BLc*32*4);           //  2 MB
  bf16*  dbuf2    = (bf16* )carve((size_t)2*BLc*DIc*2);          // 32 MB
  float* hfin2    = (float*)carve((size_t)2*Pseg*Bc*DIc*16*4);   // 16 MB (h0 in place)
  float* sdtot2   = (float*)carve((size_t)2*Pseg*Bc*DIc*4);      //  1 MB
  bf16*  ybf2     = (bf16* )carve((size_t)2*BLc*DIc*2);          // 32 MB
  bf16*  wbf      = (bf16* )carve((size_t)W_TOTAL*2);            // ~11 MB
  bf16*  wcomp    = (bf16* )carve((size_t)2*DIc*DIc*2);          //  4 MB
  // tail overlays in xzb region (free after scanC):
  float* mixout   = (float*)xzb;                                 // 16 MB
  float* delta    = (float*)xzb + (size_t)BLc*DIMc;              // 16 MB
  bf16*  tbufb    = (bf16*)((float*)xzb + (size_t)2*BLc*DIMc);   //  8 MB
  bf16*  ffnhidb  = (bf16*)((float*)xzb + (size_t)3*BLc*DIMc);   // 16 MB

  const bf16* inw_bf  = wbf + W_INW_OFF;   // (4096, 512) both dirs contiguous
  const bf16* outw_bf = wbf + W_OUTW_OFF;
  const bf16* mix_bf  = wbf + W_MIX_OFF;   // (512, 1536)
  const bf16* f1_bf   = wbf + W_F1_OFF;
  const bf16* f2_bf   = wbf + W_F2_OFF;
  const bf16* xp_bf   = wbf + W_XP_OFF;
  const bf16* pw2_bf  = wbf + W_PW2_OFF;

  // 0) weights -> bf16 ; composite dt weight
  cvt_weights_k<<<(W_TOTAL+255)/256, 256, 0, stream>>>(
      m_in_w, m_out_w, mix_w, ffn_w1, ffn_w2, m_xproj_w, pos_w2, wbf);
  dtw_comp_k<<<(2*DIc*DIc)/256, 256, 0, stream>>>(m_dt_w, m_xproj_w, wcomp);

  // 1) positional embedding
  pos_hidden_k<<<Lc, 256, 0, stream>>>(pos_w1, pos_b1, poshidb);
  mg128(poshidb, DIMc, pw2_bf, DIMc, pos, posb, DIMc, Lc, DIMc, DIMc,
        pos_b2, nullptr, 0, RM_ALL, 0, stream);
  // posmix = pos @ mix_w[:,1024:1536]^T  (1024 x 512, K=512)
  mg128(posb, DIMc, mix_bf + 1024, 3*DIMc, posmix, nullptr, DIMc, Lc, DIMc, DIMc,
        nullptr, nullptr, 0, RM_ALL, 0, stream);

  // 2) scan_in = LN(tokens) + pos -> bf16
  ln_in_k<<<BLc, 256, 0, stream>>>(tokens, in_g, in_b, pos, scaninb);

  // 3) merged in-proj for BOTH dirs: xz = scanin @ in_w^T  (8192 x 4096, K=512)
  mg128(scaninb, DIMc, inw_bf, DIMc, nullptr, xzb, 2*2*DIc, BLc, 2*2*DIc, DIMc,
        nullptr, nullptr, 0, RM_ALL, 0, stream);

  // 4) conv both dirs (8 ch/thread, vectorized)
  conv2_k<<<dim3((BLc*DIc)/(8*256), 2), 256, 0, stream>>>(xzb, xcb2, m_conv_w, m_conv_b);

  // 5) projbc both dirs: (8192 x 32, K=1024) batched
  mg_n32b(xcb2, DIc, (long)BLc*DIc, xp_bf + (size_t)32*DIc, DIc, (long)64*DIc,
          projf2, 32, (long)BLc*32, BLc, DIc, 2, stream);

  // 6) delta both dirs: softplus(xc @ wcomp^T + dt_b) -> bf16, batched (K=1024)
  mg128b(xcb2, DIc, (long)BLc*DIc, wcomp, DIc, (long)DIc*DIc,
         nullptr, dbuf2, DIc, (long)BLc*DIc, BLc, DIc, DIc, 2,
         m_dt_b, (long)DIc, nullptr, 0, RM_ALL, 2, stream);

  // 7) chunked scan, both dirs batched: A -> B (in place) -> C
  scanA_k<<<dim3(DIc/256, Bc, 32), 256, 0, stream>>>(
      projf2, dbuf2, xcb2, m_A_log, hfin2, sdtot2);
  scanB_k<<<(2*Bc*DIc*16)/256, 256, 0, stream>>>(hfin2, sdtot2, m_A_log);
  scanC_k<<<dim3(DIc/256, Bc, 32), 256, 0, stream>>>(
      projf2, dbuf2, xcb2, xzb, hfin2, m_A_log, m_D, ybf2);

  // 8) out-proj both dirs batched: concat[:, dir*512:+512] = y @ out_w^T (K=1024)
  mg128b(ybf2, DIc, (long)BLc*DIc, outw_bf, DIc, (long)DIMc*DIc,
         nullptr, concatb, 2*DIMc, (long)DIMc, BLc, DIMc, DIc, 2,
         nullptr, 0, nullptr, 0, RM_ALL, 0, stream);

  // 9) mixout = concat2 @ mix_w[:, :1024]^T + mix_b + posmix[l]  (K=1024)
  mg128(concatb, 2*DIMc, mix_bf, 3*DIMc, mixout, nullptr, DIMc, BLc, DIMc, 2*DIMc,
        mix_b, posmix, DIMc, Lc-1, 0, stream);

  // 10) delta = LN_dn(mixout) ; tbuf = LN_fn(delta)
  ln_dnfn_k<<<BLc, 256, 0, stream>>>(mixout, dn_g, dn_b, fn_g, fn_b, delta, tbufb);

  // 11) ffnhid = gelu(tbuf @ ffn_w1^T + b1)  (8192 x 1024, K=512)
  mg128(tbufb, DIMc, f1_bf, DIMc, nullptr, ffnhidb, HIDc, BLc, HIDc, DIMc,
        ffn_b1, nullptr, 0, RM_ALL, 1, stream);

  // 12) out = delta + ffnhid @ ffn_w2^T + b2  (8192 x 512, K=1024)
  mg128(ffnhidb, HIDc, f2_bf, HIDc, out, nullptr, DIMc, BLc, DIMc, HIDc,
        ffn_b2, delta, DIMc, RM_ALL, 0, stream);
}